// Round 8
// baseline (331.221 us; speedup 1.0000x reference)
//
#include <hip/hip_runtime.h>
#include <hip/hip_bf16.h>

#define B_ 2
#define C_ 20000
#define H_ 64
#define M_ 8
#define E_ 200000
#define P_ 3
#define EPS_ 1e-12f

typedef __attribute__((ext_vector_type(8))) short short8;
typedef __attribute__((ext_vector_type(4))) float float4v;

__device__ __forceinline__ float silu_(float x) {
    return x / (1.f + __expf(-x));
}
__device__ __forceinline__ unsigned short f2b(float f) {
    unsigned u = __float_as_uint(f);
    unsigned r = (u + 0x7FFF + ((u >> 16) & 1)) >> 16;   // RNE fp32->bf16
    return (unsigned short)r;
}
__device__ __forceinline__ float b2f(unsigned short h) {
    return __uint_as_float(((unsigned)h) << 16);
}
__device__ __forceinline__ unsigned pk2u(float a, float b) {
    __hip_bfloat162 h = __float22bfloat162_rn(make_float2(a, b)); // v_cvt_pk_bf16_f32
    unsigned u; __builtin_memcpy(&u, &h, sizeof(u)); return u;
}

// bf16 B-fragment-swizzled weights (K multiples of 32; W1 rows 128..131 on VALU)
#define W1S_OFF 0
#define W2S_OFF 8192
#define P1S_OFF 12288
#define U1S_OFF 16384
#define U2S_OFF 24576
#define WBUF_ELEMS 28672

// combo_kernel block ranges (all parts independent)
#define NB_PREP   120                    // 28672 weight-frag elems
#define NB_FEATB  2500                   // B*C*64/4 = 640000 threads
#define NB_DESC   157                    // ceil(B*C/256)
#define NB_HIST   782                    // ceil(E/256)
#define NB_COMBO  (NB_PREP + NB_FEATB + NB_DESC + NB_HIST)

__global__ __launch_bounds__(256) void combo_kernel(
    const float* __restrict__ W1, const float* __restrict__ W2,
    const float* __restrict__ P1, const float* __restrict__ U1,
    const float* __restrict__ U2, unsigned short* __restrict__ wbuf,
    const float* __restrict__ feat, unsigned short* __restrict__ featb,
    const float* __restrict__ pos, const int* __restrict__ cni,
    const float* __restrict__ mask, float* __restrict__ desc,
    const int* __restrict__ ei, int* __restrict__ cnt)
{
    const int bid = blockIdx.x;
    if (bid < NB_PREP) {
        // ---- weight swizzle -> bf16 B-fragments
        int t = bid * 256 + threadIdx.x;
        if (t >= WBUF_ELEMS) return;
        const float* W; int e;
        if (t < W2S_OFF)      { W = W1; e = t; }
        else if (t < U1S_OFF) { W = (t < P1S_OFF) ? W2 : P1; e = (t < P1S_OFF) ? t - W2S_OFF : t - P1S_OFF; }
        else if (t < U2S_OFF) { W = U1; e = t - U1S_OFF; }
        else                  { W = U2; e = t - U2S_OFF; }
        int j = e & 7, lane = (e >> 3) & 63, nt = (e >> 9) & 3, kk = e >> 11;
        int k = kk * 32 + ((lane >> 4) * 8) + j;
        int n = nt * 16 + (lane & 15);
        wbuf[t] = f2b(W[k * 64 + n]);
    } else if (bid < NB_PREP + NB_FEATB) {
        // ---- features -> bf16 cache (coalesced)
        int t = (bid - NB_PREP) * 256 + threadIdx.x;   // < 640000 exactly
        float4 v = *(const float4*)&feat[(size_t)t * 4];
        *(uint2*)&featb[(size_t)t * 4] = make_uint2(pk2u(v.x, v.y), pk2u(v.z, v.w));
    } else if (bid < NB_PREP + NB_FEATB + NB_DESC) {
        // ---- per-(b,cell) descriptor: 8x(x,y,z,m) + centroid + own pos
        int tid = (bid - NB_PREP - NB_FEATB) * 256 + threadIdx.x;
        if (tid >= B_ * C_) return;
        int b = tid / C_, c = tid - b * C_;
        const float* pb = pos + (size_t)b * C_ * P_;
        float4* D = (float4*)(desc + (size_t)tid * 40);
        int4 n0 = *(const int4*)&cni[c*8];
        int4 n1 = *(const int4*)&cni[c*8 + 4];
        float4 m0 = *(const float4*)&mask[c*8];
        float4 m1 = *(const float4*)&mask[c*8 + 4];
        int ni[8] = {n0.x, n0.y, n0.z, n0.w, n1.x, n1.y, n1.z, n1.w};
        float mm[8] = {m0.x, m0.y, m0.z, m0.w, m1.x, m1.y, m1.z, m1.w};
        float sx = 0.f, sy = 0.f, sz = 0.f, sm = 0.f;
        #pragma unroll
        for (int m = 0; m < 8; ++m) {
            float x = pb[ni[m]*3+0], y = pb[ni[m]*3+1], z = pb[ni[m]*3+2];
            D[m] = make_float4(x, y, z, mm[m]);
            sx += x * mm[m]; sy += y * mm[m]; sz += z * mm[m]; sm += mm[m];
        }
        float inv = 1.f / fmaxf(sm, EPS_);
        D[8] = make_float4(sx * inv, sy * inv, sz * inv, sm);
        D[9] = make_float4(pb[c*3+0], pb[c*3+1], pb[c*3+2], 0.f);
    } else {
        // ---- dst histogram
        int e = (bid - NB_PREP - NB_FEATB - NB_DESC) * 256 + threadIdx.x;
        if (e >= E_) return;
        atomicAdd(&cnt[ei[E_ + e]], 1);
    }
}

// ---------------------------------------------------------------------------
// alloc: wave-scan + one atomic bump per wave -> cursor (segment order free)
// ---------------------------------------------------------------------------
__global__ __launch_bounds__(256) void alloc_kernel(
    const int* __restrict__ cnt, int* __restrict__ cursor, int* __restrict__ total)
{
    int idx = blockIdx.x * 256 + threadIdx.x;
    int lane = threadIdx.x & 63;
    int v = (idx < C_) ? cnt[idx] : 0;
    int inc = v;
    #pragma unroll
    for (int s = 1; s < 64; s <<= 1) {
        int n = __shfl_up(inc, s);
        if (lane >= s) inc += n;
    }
    int wtot = __shfl(inc, 63);
    int base = 0;
    if (lane == 0) base = atomicAdd(total, wtot);
    base = __shfl(base, 0);
    if (idx < C_) cursor[idx] = base + inc - v;
}

__global__ __launch_bounds__(256) void scatter_kernel(
    const int* __restrict__ ei, int* __restrict__ cursor,
    int2* __restrict__ sedge)
{
    int e = blockIdx.x * 256 + threadIdx.x;
    if (e >= E_) return;
    int s = ei[e], d = ei[E_ + e];
    int slot = atomicAdd(&cursor[d], 1);
    sedge[slot] = make_int2(s, d);
}

// ---------------------------------------------------------------------------
// Edge kernel: 128 thr = 2 independent waves, 64 edges per wave.
// Geometry: per-lane ownership (lane = edge) -> no quad duplication, no
// butterflies; iv+rel parked in LDS fp32 slab. Then 4 sequential 16-edge
// MFMA MLP sub-tiles + per-tile segmented aggregation (dst-sorted).
// Barrier-free: all LDS strictly wave-private, DS ops in-order per wave.
// ---------------------------------------------------------------------------
__global__ __launch_bounds__(128, 4) void edge_kernel(
    const unsigned short* __restrict__ featb,
    const int2* __restrict__ sedge,
    const float* __restrict__ desc,
    const unsigned short* __restrict__ wbuf, const float* __restrict__ W1,
    const float* __restrict__ b1, const float* __restrict__ b2,
    const float* __restrict__ pb1, const float* __restrict__ P2,
    const float* __restrict__ pb2,
    float* __restrict__ aggf, float* __restrict__ out_pos)
{
    __shared__ __align__(16) unsigned short lds[2 * 4352];   // 17408 B

    const int tid  = threadIdx.x;
    const int w    = tid >> 6;
    const int lane = tid & 63;
    const int q    = lane >> 4;
    const int l16  = lane & 15;

    const int wid  = blockIdx.x * 2 + w;           // global wave id, 0..6249
    const int b    = wid / (E_ / 64);
    const int i0   = (wid - b * (E_ / 64)) * 64;

    const int2 sd  = sedge[i0 + lane];
    const int s_l  = sd.x;
    const int d_l  = sd.y;
    const unsigned short* fb = featb + (size_t)b * C_ * H_;

    unsigned short* Xw = lds + w * 4352;   // X: 16 rows x 136 (tile-local)
    unsigned short* Hw = Xw + 2176;        // H: 16 rows x 72
    unsigned short* Mw = Xw;               // M aliases X (dep-chain safe)
    float* IVw = (float*)(Xw + 3328);      // 64 slots x 8 fp32 (iv4 + rel3 + pad)

    // ================= geometry: lane owns edge i0+lane ======================
    const float4* Ds = (const float4*)(desc + ((size_t)b * C_ + s_l) * 40);
    const float4* Dd = (const float4*)(desc + ((size_t)b * C_ + d_l) * 40);
    const float INFV = __builtin_inff();
    float4 S[8], D[8];
    #pragma unroll
    for (int i = 0; i < 8; ++i) { S[i] = Ds[i]; D[i] = Dd[i]; }
    float a_i[8], infm_i[8], rowmin[8];
    #pragma unroll
    for (int i = 0; i < 8; ++i) {
        a_i[i] = S[i].x*S[i].x + S[i].y*S[i].y + S[i].z*S[i].z + EPS_;
        infm_i[i] = (S[i].w > 0.f) ? 0.f : INFV;
        rowmin[i] = INFV;
    }
    float pair = 0.f, hyx = 0.f;
    #pragma unroll
    for (int j = 0; j < 8; ++j) {
        float4 Dj = D[j];
        float dp2 = Dj.x*Dj.x + Dj.y*Dj.y + Dj.z*Dj.z;
        float infm_j = (Dj.w > 0.f) ? 0.f : INFV;
        float colmin = INFV, psum = 0.f;
        #pragma unroll
        for (int i = 0; i < 8; ++i) {
            float cr = S[i].x*Dj.x + S[i].y*Dj.y + S[i].z*Dj.z;
            float t  = (a_i[i] + dp2) - 2.f*cr;
            float dd = sqrtf(fmaxf(t, EPS_));      // == sqrt(max(q,0)+EPS)
            psum = fmaf(dd, S[i].w, psum);
            rowmin[i] = fminf(rowmin[i], dd + infm_j);
            colmin    = fminf(colmin,    dd + infm_i[i]);
        }
        pair = fmaf(Dj.w, psum, pair);
        hyx = fmaxf(hyx, (Dj.w > 0.f) ? colmin : 0.f);
    }
    float hxy = 0.f;
    #pragma unroll
    for (int i = 0; i < 8; ++i)
        hxy = fmaxf(hxy, (S[i].w > 0.f) ? rowmin[i] : 0.f);
    float4 Sc = Ds[8], Dc = Dd[8];
    float cdx = Sc.x - Dc.x, cdy = Sc.y - Dc.y, cdz = Sc.z - Dc.z;
    float4 Sp = Ds[9], Dp = Dd[9];
    const float relx = Sp.x - Dp.x, rely = Sp.y - Dp.y, relz = Sp.z - Dp.z;
    {
        float ivx = sqrtf(relx*relx + rely*rely + relz*relz);   // dist
        float ivz = sqrtf(cdx*cdx + cdy*cdy + cdz*cdz);         // centroid
        float ivw = fmaxf(hxy, hyx);                            // hausdorff
        *(float4*)&IVw[lane*8]     = make_float4(ivx, pair, ivz, ivw);
        *(float4*)&IVw[lane*8 + 4] = make_float4(relx, rely, relz, 0.f);
    }

    // ================= hoisted constants (loaded after geometry regs die) ====
    float b1v[4], b2v[4], pb1v[4], p2v[4];
    float wta[4], wtb[4], wtc[4], wtd[4];
    #pragma unroll
    for (int nt = 0; nt < 4; ++nt) {
        b1v[nt]  = b1[nt*16 + l16];
        b2v[nt]  = b2[nt*16 + l16];
        pb1v[nt] = pb1[nt*16 + l16];
        p2v[nt]  = P2[nt*16 + l16];
        wta[nt]  = W1[128*64 + nt*16 + l16];
        wtb[nt]  = W1[129*64 + nt*16 + l16];
        wtc[nt]  = W1[130*64 + nt*16 + l16];
        wtd[nt]  = W1[131*64 + nt*16 + l16];
    }
    const float pb2v = pb2[0];

    float* aggB = aggf + (size_t)b * C_ * 64;
    float* opB  = out_pos + (size_t)b * C_ * 3;
    const int rr4 = lane >> 4, c4 = lane & 15;

    // ================= 4 sub-tiles of 16 edges ===============================
    for (int it = 0; it < 4; ++it) {
        // ---- stage X = [h_src | h_dst]
        #pragma unroll
        for (int it2 = 0; it2 < 4; ++it2) {
            int rloc = it2 * 4 + rr4;
            int sr = __shfl(s_l, it*16 + rloc);
            int dr = __shfl(d_l, it*16 + rloc);
            *(uint2*)&Xw[rloc*136 + c4*4]      = *(const uint2*)&fb[(size_t)sr*64 + c4*4];
            *(uint2*)&Xw[rloc*136 + 64 + c4*4] = *(const uint2*)&fb[(size_t)dr*64 + c4*4];
        }

        // ---- layer 1: MFMA k<128 + fp32 invariant tail (iv from LDS)
        float4v acc[4];
        #pragma unroll
        for (int nt = 0; nt < 4; ++nt)
            acc[nt] = (float4v){b1v[nt], b1v[nt], b1v[nt], b1v[nt]};
        #pragma unroll
        for (int kk = 0; kk < 4; ++kk) {
            short8 a = *(const short8*)&Xw[l16*136 + kk*32 + q*8];
            #pragma unroll
            for (int nt = 0; nt < 4; ++nt) {
                short8 bf = *(const short8*)&wbuf[W1S_OFF + (((kk*4 + nt)*64) + lane) * 8];
                acc[nt] = __builtin_amdgcn_mfma_f32_16x16x32_bf16(a, bf, acc[nt], 0, 0, 0);
            }
        }
        #pragma unroll
        for (int i = 0; i < 4; ++i) {
            float4 iv = *(const float4*)&IVw[(it*16 + q*4 + i) * 8];
            #pragma unroll
            for (int nt = 0; nt < 4; ++nt)
                acc[nt][i] += iv.x*wta[nt] + iv.y*wtb[nt] + iv.z*wtc[nt] + iv.w*wtd[nt];
        }
        #pragma unroll
        for (int nt = 0; nt < 4; ++nt)
            #pragma unroll
            for (int i = 0; i < 4; ++i)
                Hw[(q*4 + i)*72 + nt*16 + l16] = f2b(silu_(acc[nt][i]));

        // ---- layer 2 -> messages
        float4v mac[4];
        #pragma unroll
        for (int nt = 0; nt < 4; ++nt)
            mac[nt] = (float4v){b2v[nt], b2v[nt], b2v[nt], b2v[nt]};
        #pragma unroll
        for (int kk = 0; kk < 2; ++kk) {
            short8 a = *(const short8*)&Hw[l16*72 + kk*32 + q*8];
            #pragma unroll
            for (int nt = 0; nt < 4; ++nt) {
                short8 bf = *(const short8*)&wbuf[W2S_OFF + (((kk*4 + nt)*64) + lane) * 8];
                mac[nt] = __builtin_amdgcn_mfma_f32_16x16x32_bf16(a, bf, mac[nt], 0, 0, 0);
            }
        }
        #pragma unroll
        for (int nt = 0; nt < 4; ++nt)
            #pragma unroll
            for (int i = 0; i < 4; ++i)
                Mw[(q*4 + i)*72 + nt*16 + l16] = f2b(mac[nt][i]);

        // ---- gate: wt = tanh(silu(M @ P1 + pb1) @ P2 + pb2)
        float4v gac[4];
        #pragma unroll
        for (int nt = 0; nt < 4; ++nt)
            gac[nt] = (float4v){pb1v[nt], pb1v[nt], pb1v[nt], pb1v[nt]};
        #pragma unroll
        for (int kk = 0; kk < 2; ++kk) {
            short8 a = *(const short8*)&Mw[l16*72 + kk*32 + q*8];
            #pragma unroll
            for (int nt = 0; nt < 4; ++nt) {
                short8 bf = *(const short8*)&wbuf[P1S_OFF + (((kk*4 + nt)*64) + lane) * 8];
                gac[nt] = __builtin_amdgcn_mfma_f32_16x16x32_bf16(a, bf, gac[nt], 0, 0, 0);
            }
        }
        #pragma unroll
        for (int i = 0; i < 4; ++i) {
            float p = 0.f;
            #pragma unroll
            for (int nt = 0; nt < 4; ++nt) p += silu_(gac[nt][i]) * p2v[nt];
            p += __shfl_xor(p, 8);
            p += __shfl_xor(p, 4);
            p += __shfl_xor(p, 2);
            p += __shfl_xor(p, 1);
            float wt = tanhf(p + pb2v);
            if (l16 == 0) *(float*)&Mw[(q*4 + i)*72 + 64] = wt;   // park
        }

        // ---- segmented aggregation over this tile's 16 edges
        float mrow[16];
        #pragma unroll
        for (int rr = 0; rr < 16; ++rr) mrow[rr] = b2f(Mw[rr*72 + lane]);
        float wtl = *(const float*)&Mw[l16*72 + 64];   // lane l16 = row l16's wt

        int dprev = __shfl(d_l, it*16);
        float colacc = 0.f, pxa = 0.f, pya = 0.f, pza = 0.f;
        #pragma unroll
        for (int rr = 0; rr < 16; ++rr) {
            int dcur = __shfl(d_l, it*16 + rr);        // wave-uniform
            if (dcur != dprev) {                       // uniform branch
                atomicAdd(&aggB[(size_t)dprev * 64 + lane], colacc);
                if (lane < 3) {
                    float v = (lane == 0) ? pxa : (lane == 1) ? pya : pza;
                    atomicAdd(&opB[(size_t)dprev * 3 + lane], v);
                }
                colacc = 0.f; pxa = 0.f; pya = 0.f; pza = 0.f;
                dprev = dcur;
            }
            float wt = __shfl(wtl, rr);
            colacc += mrow[rr];
            pxa = fmaf(wt, __shfl(relx, it*16 + rr), pxa);
            pya = fmaf(wt, __shfl(rely, it*16 + rr), pya);
            pza = fmaf(wt, __shfl(relz, it*16 + rr), pza);
        }
        atomicAdd(&aggB[(size_t)dprev * 64 + lane], colacc);
        if (lane < 3) {
            float v = (lane == 0) ? pxa : (lane == 1) ? pya : pza;
            atomicAdd(&opB[(size_t)dprev * 3 + lane], v);
        }
    }
}

// ---------------------------------------------------------------------------
// Node update via MFMA, barrier-free wave-private strips (R6 form).
// ---------------------------------------------------------------------------
__global__ __launch_bounds__(256) void node_kernel(
    const float* __restrict__ feat, const unsigned short* __restrict__ featb,
    const float* __restrict__ aggf, const float* __restrict__ deg,
    const unsigned short* __restrict__ wbuf,
    const float* __restrict__ ub1, const float* __restrict__ ub2,
    float* __restrict__ out_feat)
{
    __shared__ unsigned short lds[4 * 3328];

    const int tid  = threadIdx.x;
    const int w    = tid >> 6;
    const int lane = tid & 63;
    const int q    = lane >> 4;
    const int l16  = lane & 15;
    const int g0   = blockIdx.x * 64;

    unsigned short* Xw = lds + w * 3328;
    unsigned short* Hw = Xw + 2176;

    const int rr4 = lane >> 4, c4 = lane & 15;
    #pragma unroll
    for (int it = 0; it < 4; ++it) {
        int rloc = it * 4 + rr4;
        int g = g0 + w*16 + rloc;
        int gc = (g >= C_) ? g - C_ : g;
        float sc = 1.f / fmaxf(deg[gc], 1.f);
        uint2  vf = *(const uint2*)&featb[(size_t)g * 64 + c4 * 4];
        float4 va = *(const float4*)&aggf[(size_t)g * 64 + c4 * 4];
        *(uint2*)&Xw[rloc*136 + c4*4]      = vf;
        *(uint2*)&Xw[rloc*136 + 64 + c4*4] =
            make_uint2(pk2u(va.x*sc, va.y*sc), pk2u(va.z*sc, va.w*sc));
    }

    float4v acc[4];
    #pragma unroll
    for (int nt = 0; nt < 4; ++nt) {
        float bv = ub1[nt*16 + l16];
        acc[nt] = (float4v){bv, bv, bv, bv};
    }
    #pragma unroll
    for (int kk = 0; kk < 4; ++kk) {
        short8 a = *(const short8*)&Xw[l16*136 + kk*32 + q*8];
        #pragma unroll
        for (int nt = 0; nt < 4; ++nt) {
            short8 bf = *(const short8*)&wbuf[U1S_OFF + (((kk*4 + nt)*64) + lane) * 8];
            acc[nt] = __builtin_amdgcn_mfma_f32_16x16x32_bf16(a, bf, acc[nt], 0, 0, 0);
        }
    }
    #pragma unroll
    for (int nt = 0; nt < 4; ++nt)
        #pragma unroll
        for (int i = 0; i < 4; ++i)
            Hw[(q*4 + i)*72 + nt*16 + l16] = f2b(silu_(acc[nt][i]));

    float4v oac[4];
    #pragma unroll
    for (int nt = 0; nt < 4; ++nt) {
        float bv = ub2[nt*16 + l16];
        oac[nt] = (float4v){bv, bv, bv, bv};
    }
    #pragma unroll
    for (int kk = 0; kk < 2; ++kk) {
        short8 a = *(const short8*)&Hw[l16*72 + kk*32 + q*8];
        #pragma unroll
        for (int nt = 0; nt < 4; ++nt) {
            short8 bf = *(const short8*)&wbuf[U2S_OFF + (((kk*4 + nt)*64) + lane) * 8];
            oac[nt] = __builtin_amdgcn_mfma_f32_16x16x32_bf16(a, bf, oac[nt], 0, 0, 0);
        }
    }
    #pragma unroll
    for (int nt = 0; nt < 4; ++nt)
        #pragma unroll
        for (int i = 0; i < 4; ++i) {
            size_t idx = (size_t)(g0 + w*16 + q*4 + i) * 64 + nt*16 + l16;
            out_feat[idx] = feat[idx] + oac[nt][i];
        }
}

extern "C" void kernel_launch(void* const* d_in, const int* in_sizes, int n_in,
                              void* d_out, int out_size, void* d_ws, size_t ws_size,
                              hipStream_t stream) {
    const float* feat = (const float*)d_in[0];
    const float* pos  = (const float*)d_in[1];
    const int*   ei   = (const int*)d_in[2];
    const float* deg  = (const float*)d_in[3];
    const int*   cni  = (const int*)d_in[4];
    const float* mask = (const float*)d_in[5];
    const float* W1   = (const float*)d_in[6];
    const float* b1   = (const float*)d_in[7];
    const float* W2   = (const float*)d_in[8];
    const float* b2   = (const float*)d_in[9];
    const float* P1   = (const float*)d_in[10];
    const float* pb1  = (const float*)d_in[11];
    const float* P2   = (const float*)d_in[12];
    const float* pb2  = (const float*)d_in[13];
    const float* U1   = (const float*)d_in[14];
    const float* ub1  = (const float*)d_in[15];
    const float* U2   = (const float*)d_in[16];
    const float* ub2  = (const float*)d_in[17];

    float* out_feat = (float*)d_out;                       // B*C*H
    float* out_pos  = out_feat + (size_t)B_ * C_ * H_;     // B*C*P

    // workspace layout (~24 MB)
    float* desc = (float*)d_ws;                                  // B*C*40 fp32
    float* aggf = desc + (size_t)B_ * C_ * 40;                   // B*C*64 fp32
    unsigned short* featb = (unsigned short*)(aggf + (size_t)B_ * C_ * 64); // B*C*64
    unsigned short* wbuf  = featb + (size_t)B_ * C_ * 64;        // 28672
    int* cnt    = (int*)(wbuf + WBUF_ELEMS);                     // C
    int* total  = cnt + C_;                                      // 1
    int* cursor = total + 1;                                     // C
    int2* sedge = (int2*)(cursor + C_);                          // E int2

    hipMemsetAsync(cnt, 0, (C_ + 1) * sizeof(int), stream);      // cnt + total
    hipMemsetAsync(aggf, 0, (size_t)B_ * C_ * 64 * sizeof(float), stream);
    hipMemcpyAsync(out_pos, pos, (size_t)B_ * C_ * P_ * sizeof(float),
                   hipMemcpyDeviceToDevice, stream);

    combo_kernel<<<NB_COMBO, 256, 0, stream>>>(
        W1, W2, P1, U1, U2, wbuf, feat, featb, pos, cni, mask, desc, ei, cnt);

    alloc_kernel<<<(C_ + 255) / 256, 256, 0, stream>>>(cnt, cursor, total);
    scatter_kernel<<<(E_ + 255) / 256, 256, 0, stream>>>(ei, cursor, sedge);

    edge_kernel<<<(B_ * E_) / 128, 128, 0, stream>>>(
        featb, sedge, desc, wbuf, W1, b1, b2, pb1, P2, pb2, aggf, out_pos);

    node_kernel<<<(B_ * C_) / 64, 256, 0, stream>>>(
        feat, featb, aggf, deg, wbuf, ub1, ub2, out_feat);
}

// Round 9
// 247.261 us; speedup vs baseline: 1.3396x; 1.3396x over previous
//
#include <hip/hip_runtime.h>
#include <hip/hip_bf16.h>

#define B_ 2
#define C_ 20000
#define H_ 64
#define M_ 8
#define E_ 200000
#define P_ 3
#define EPS_ 1e-12f
#define ET_ (E_ / 64)   // edge tiles per batch = 3125

typedef __attribute__((ext_vector_type(8))) short short8;
typedef __attribute__((ext_vector_type(4))) float float4v;

__device__ __forceinline__ float silu_(float x) {
    return x / (1.f + __expf(-x));
}
__device__ __forceinline__ float tanh_fast_(float x) {
    float ex = __expf(2.f * x);
    return 1.f - 2.f / (ex + 1.f);
}
__device__ __forceinline__ unsigned short f2b(float f) {
    unsigned u = __float_as_uint(f);
    unsigned r = (u + 0x7FFF + ((u >> 16) & 1)) >> 16;   // RNE fp32->bf16
    return (unsigned short)r;
}
__device__ __forceinline__ float b2f(unsigned short h) {
    return __uint_as_float(((unsigned)h) << 16);
}
__device__ __forceinline__ unsigned pk2u(float a, float b) {
    __hip_bfloat162 h = __float22bfloat162_rn(make_float2(a, b)); // v_cvt_pk_bf16_f32
    unsigned u; __builtin_memcpy(&u, &h, sizeof(u)); return u;
}

// bf16 B-fragment-swizzled weights (K multiples of 32; W1 rows 128..131 on VALU)
#define W1S_OFF 0
#define W2S_OFF 8192
#define P1S_OFF 12288
#define U1S_OFF 16384
#define U2S_OFF 24576
#define WBUF_ELEMS 28672

// combo_kernel block ranges (all parts independent)
#define NB_PREP   120                    // 28672 weight-frag elems
#define NB_FEATB  2500                   // B*C*64/4 = 640000 threads
#define NB_DESC   157                    // ceil(B*C/256)
#define NB_HIST   782                    // ceil(E/256)
#define NB_COMBO  (NB_PREP + NB_FEATB + NB_DESC + NB_HIST)

// geom_kernel block ranges
#define NB_GEOM   3125                   // B*E/256
#define NB_AGGZ   2500                   // zero aggf: B*C*64/4 float4
#define NB_PCPY   118                    // out_pos = pos: 30000 float4
#define NB_GEOMK  (NB_GEOM + NB_AGGZ + NB_PCPY)

__global__ __launch_bounds__(256) void combo_kernel(
    const float* __restrict__ W1, const float* __restrict__ W2,
    const float* __restrict__ P1, const float* __restrict__ U1,
    const float* __restrict__ U2, unsigned short* __restrict__ wbuf,
    const float* __restrict__ feat, unsigned short* __restrict__ featb,
    const float* __restrict__ pos, const int* __restrict__ cni,
    const float* __restrict__ mask, float* __restrict__ desc,
    const int* __restrict__ ei, int* __restrict__ cnt)
{
    const int bid = blockIdx.x;
    if (bid < NB_PREP) {
        // ---- weight swizzle -> bf16 B-fragments
        int t = bid * 256 + threadIdx.x;
        if (t >= WBUF_ELEMS) return;
        const float* W; int e;
        if (t < W2S_OFF)      { W = W1; e = t; }
        else if (t < U1S_OFF) { W = (t < P1S_OFF) ? W2 : P1; e = (t < P1S_OFF) ? t - W2S_OFF : t - P1S_OFF; }
        else if (t < U2S_OFF) { W = U1; e = t - U1S_OFF; }
        else                  { W = U2; e = t - U2S_OFF; }
        int j = e & 7, lane = (e >> 3) & 63, nt = (e >> 9) & 3, kk = e >> 11;
        int k = kk * 32 + ((lane >> 4) * 8) + j;
        int n = nt * 16 + (lane & 15);
        wbuf[t] = f2b(W[k * 64 + n]);
    } else if (bid < NB_PREP + NB_FEATB) {
        // ---- features -> bf16 cache (coalesced)
        int t = (bid - NB_PREP) * 256 + threadIdx.x;   // < 640000 exactly
        float4 v = *(const float4*)&feat[(size_t)t * 4];
        *(uint2*)&featb[(size_t)t * 4] = make_uint2(pk2u(v.x, v.y), pk2u(v.z, v.w));
    } else if (bid < NB_PREP + NB_FEATB + NB_DESC) {
        // ---- per-(b,cell) descriptor: 8x(x,y,z,m) + centroid + own pos
        int tid = (bid - NB_PREP - NB_FEATB) * 256 + threadIdx.x;
        if (tid >= B_ * C_) return;
        int b = tid / C_, c = tid - b * C_;
        const float* pb = pos + (size_t)b * C_ * P_;
        float4* D = (float4*)(desc + (size_t)tid * 40);
        int4 n0 = *(const int4*)&cni[c*8];
        int4 n1 = *(const int4*)&cni[c*8 + 4];
        float4 m0 = *(const float4*)&mask[c*8];
        float4 m1 = *(const float4*)&mask[c*8 + 4];
        int ni[8] = {n0.x, n0.y, n0.z, n0.w, n1.x, n1.y, n1.z, n1.w};
        float mm[8] = {m0.x, m0.y, m0.z, m0.w, m1.x, m1.y, m1.z, m1.w};
        float sx = 0.f, sy = 0.f, sz = 0.f, sm = 0.f;
        #pragma unroll
        for (int m = 0; m < 8; ++m) {
            float x = pb[ni[m]*3+0], y = pb[ni[m]*3+1], z = pb[ni[m]*3+2];
            D[m] = make_float4(x, y, z, mm[m]);
            sx += x * mm[m]; sy += y * mm[m]; sz += z * mm[m]; sm += mm[m];
        }
        float inv = 1.f / fmaxf(sm, EPS_);
        D[8] = make_float4(sx * inv, sy * inv, sz * inv, sm);
        D[9] = make_float4(pb[c*3+0], pb[c*3+1], pb[c*3+2], 0.f);
    } else {
        // ---- dst histogram
        int e = (bid - NB_PREP - NB_FEATB - NB_DESC) * 256 + threadIdx.x;
        if (e >= E_) return;
        atomicAdd(&cnt[ei[E_ + e]], 1);
    }
}

// ---------------------------------------------------------------------------
// alloc: wave-scan + one atomic bump per wave -> cursor (segment order free)
// ---------------------------------------------------------------------------
__global__ __launch_bounds__(256) void alloc_kernel(
    const int* __restrict__ cnt, int* __restrict__ cursor, int* __restrict__ total)
{
    int idx = blockIdx.x * 256 + threadIdx.x;
    int lane = threadIdx.x & 63;
    int v = (idx < C_) ? cnt[idx] : 0;
    int inc = v;
    #pragma unroll
    for (int s = 1; s < 64; s <<= 1) {
        int n = __shfl_up(inc, s);
        if (lane >= s) inc += n;
    }
    int wtot = __shfl(inc, 63);
    int base = 0;
    if (lane == 0) base = atomicAdd(total, wtot);
    base = __shfl(base, 0);
    if (idx < C_) cursor[idx] = base + inc - v;
}

__global__ __launch_bounds__(256) void scatter_kernel(
    const int* __restrict__ ei, int* __restrict__ cursor,
    int2* __restrict__ sedge)
{
    int e = blockIdx.x * 256 + threadIdx.x;
    if (e >= E_) return;
    int s = ei[e], d = ei[E_ + e];
    int slot = atomicAdd(&cursor[d], 1);
    sedge[slot] = make_int2(s, d);
}

// ---------------------------------------------------------------------------
// geom: per-thread edge geometry in sorted order -> inv8 (iv4 + rel3),
// coalesced 32 B records. Also absorbs aggf-zero and out_pos=pos ranges.
// ---------------------------------------------------------------------------
__global__ __launch_bounds__(256) void geom_kernel(
    const int2* __restrict__ sedge, const float* __restrict__ desc,
    float* __restrict__ inv8,
    float* __restrict__ aggf, const float* __restrict__ pos,
    float* __restrict__ out_pos)
{
    const int bid = blockIdx.x;
    if (bid >= NB_GEOM) {
        if (bid < NB_GEOM + NB_AGGZ) {
            int t = (bid - NB_GEOM) * 256 + threadIdx.x;
            ((float4*)aggf)[t] = make_float4(0.f, 0.f, 0.f, 0.f);
        } else {
            int t = (bid - NB_GEOM - NB_AGGZ) * 256 + threadIdx.x;
            if (t < (B_ * C_ * P_) / 4)
                ((float4*)out_pos)[t] = ((const float4*)pos)[t];
        }
        return;
    }
    int gid = bid * 256 + threadIdx.x;          // < B*E
    int b = gid / E_, i = gid - b * E_;
    int2 sd = sedge[i];
    const float4* Ds = (const float4*)(desc + ((size_t)b * C_ + sd.x) * 40);
    const float4* Dd = (const float4*)(desc + ((size_t)b * C_ + sd.y) * 40);
    const float INFV = __builtin_inff();
    float4 S[8];
    float a_i[8], infm_i[8], rowmin[8];
    #pragma unroll
    for (int k = 0; k < 8; ++k) {
        S[k] = Ds[k];
        a_i[k] = S[k].x*S[k].x + S[k].y*S[k].y + S[k].z*S[k].z + EPS_;
        infm_i[k] = (S[k].w > 0.f) ? 0.f : INFV;
        rowmin[k] = INFV;
    }
    float pair = 0.f, hyx = 0.f;
    #pragma unroll
    for (int j = 0; j < 8; ++j) {
        float4 Dj = Dd[j];
        float dp2 = Dj.x*Dj.x + Dj.y*Dj.y + Dj.z*Dj.z;
        float infm_j = (Dj.w > 0.f) ? 0.f : INFV;
        float colmin = INFV, psum = 0.f;
        #pragma unroll
        for (int k = 0; k < 8; ++k) {
            float cr = S[k].x*Dj.x + S[k].y*Dj.y + S[k].z*Dj.z;
            float t  = (a_i[k] + dp2) - 2.f*cr;
            float dd = sqrtf(fmaxf(t, EPS_));
            psum = fmaf(dd, S[k].w, psum);
            rowmin[k] = fminf(rowmin[k], dd + infm_j);
            colmin    = fminf(colmin,    dd + infm_i[k]);
        }
        pair = fmaf(Dj.w, psum, pair);
        hyx = fmaxf(hyx, (Dj.w > 0.f) ? colmin : 0.f);
    }
    float hxy = 0.f;
    #pragma unroll
    for (int k = 0; k < 8; ++k)
        hxy = fmaxf(hxy, (S[k].w > 0.f) ? rowmin[k] : 0.f);
    float4 Sc = Ds[8], Dc = Dd[8];
    float cdx = Sc.x - Dc.x, cdy = Sc.y - Dc.y, cdz = Sc.z - Dc.z;
    float4 Sp = Ds[9], Dp = Dd[9];
    float relx = Sp.x - Dp.x, rely = Sp.y - Dp.y, relz = Sp.z - Dp.z;
    float dist = sqrtf(relx*relx + rely*rely + relz*relz);
    float cen  = sqrtf(cdx*cdx + cdy*cdy + cdz*cdz);
    float haus = fmaxf(hxy, hyx);
    ((float4*)inv8)[(size_t)gid * 2]     = make_float4(dist, pair, cen, haus);
    ((float4*)inv8)[(size_t)gid * 2 + 1] = make_float4(relx, rely, relz, 0.f);
}

// ---------------------------------------------------------------------------
// Edge kernel: 3 MFMA MLP stages + in-wave segmented aggregation (R6 core,
// geometry moved out). 4 independent waves/block, barrier-free wave-private
// LDS arenas; invariants read from inv8 (quad-broadcast loads).
// ---------------------------------------------------------------------------
__global__ __launch_bounds__(256) void edge_kernel(
    const unsigned short* __restrict__ featb,
    const int2* __restrict__ sedge, const float* __restrict__ inv8,
    const unsigned short* __restrict__ wbuf, const float* __restrict__ W1,
    const float* __restrict__ b1, const float* __restrict__ b2,
    const float* __restrict__ pb1, const float* __restrict__ P2,
    const float* __restrict__ pb2,
    float* __restrict__ aggf, float* __restrict__ out_pos)
{
    __shared__ unsigned short lds[4 * 3328];   // 26624 B

    const int tid  = threadIdx.x;
    const int w    = tid >> 6;
    const int lane = tid & 63;
    const int q    = lane >> 4;
    const int l16  = lane & 15;
    const int w16  = w * 16;

    const int tile = blockIdx.x;
    const int b    = tile / ET_;
    const int i0   = (tile - b * ET_) * 64;
    const int2 sd  = sedge[i0 + lane];
    const int s_l  = sd.x;
    const int d_l  = sd.y;
    const unsigned short* fb = featb + (size_t)b * C_ * H_;
    const float* ivb = inv8 + ((size_t)b * E_ + i0) * 8;

    unsigned short* Xw = lds + w * 3328;
    unsigned short* Hw = Xw + 2176;
    unsigned short* Mw = Xw;   // alias: X dead before M written (dep chain)

    // per-lane rel for edge w16+l16 (16 distinct addrs, quad-duplicated)
    float4 ivhi = *(const float4*)&ivb[(w16 + l16) * 8 + 4];
    const float relx = ivhi.x, rely = ivhi.y, relz = ivhi.z;

    // ================= stage X = [h_src | h_dst] from bf16 cache =============
    const int rr4 = lane >> 4, c4 = lane & 15;
    #pragma unroll
    for (int it = 0; it < 4; ++it) {
        int rloc = it * 4 + rr4;
        int r = w16 + rloc;
        int sr = __shfl(s_l, r);
        int dr = __shfl(d_l, r);
        uint2 vs = *(const uint2*)&fb[(size_t)sr * 64 + c4 * 4];
        uint2 vd = *(const uint2*)&fb[(size_t)dr * 64 + c4 * 4];
        *(uint2*)&Xw[rloc*136 + c4*4]      = vs;
        *(uint2*)&Xw[rloc*136 + 64 + c4*4] = vd;
    }

    // ================= layer 1: MFMA k<128 + fp32 invariant tail =============
    float4v acc[4];
    #pragma unroll
    for (int nt = 0; nt < 4; ++nt) {
        float bv = b1[nt*16 + l16];
        acc[nt] = (float4v){bv, bv, bv, bv};
    }
    #pragma unroll
    for (int kk = 0; kk < 4; ++kk) {
        short8 a = *(const short8*)&Xw[l16*136 + kk*32 + q*8];
        #pragma unroll
        for (int nt = 0; nt < 4; ++nt) {
            short8 bf = *(const short8*)&wbuf[W1S_OFF + (((kk*4 + nt)*64) + lane) * 8];
            acc[nt] = __builtin_amdgcn_mfma_f32_16x16x32_bf16(a, bf, acc[nt], 0, 0, 0);
        }
    }
    float4 iv[4];
    #pragma unroll
    for (int i = 0; i < 4; ++i)
        iv[i] = *(const float4*)&ivb[(w16 + q*4 + i) * 8];   // quad-broadcast
    #pragma unroll
    for (int nt = 0; nt < 4; ++nt) {
        float wa = W1[128*64 + nt*16 + l16];
        float wb = W1[129*64 + nt*16 + l16];
        float wc = W1[130*64 + nt*16 + l16];
        float wd = W1[131*64 + nt*16 + l16];
        #pragma unroll
        for (int i = 0; i < 4; ++i)
            acc[nt][i] += iv[i].x*wa + iv[i].y*wb + iv[i].z*wc + iv[i].w*wd;
    }
    #pragma unroll
    for (int nt = 0; nt < 4; ++nt)
        #pragma unroll
        for (int i = 0; i < 4; ++i)
            Hw[(q*4 + i)*72 + nt*16 + l16] = f2b(silu_(acc[nt][i]));

    // ================= layer 2 -> messages ===================================
    float4v mac[4];
    #pragma unroll
    for (int nt = 0; nt < 4; ++nt) {
        float bv = b2[nt*16 + l16];
        mac[nt] = (float4v){bv, bv, bv, bv};
    }
    #pragma unroll
    for (int kk = 0; kk < 2; ++kk) {
        short8 a = *(const short8*)&Hw[l16*72 + kk*32 + q*8];
        #pragma unroll
        for (int nt = 0; nt < 4; ++nt) {
            short8 bf = *(const short8*)&wbuf[W2S_OFF + (((kk*4 + nt)*64) + lane) * 8];
            mac[nt] = __builtin_amdgcn_mfma_f32_16x16x32_bf16(a, bf, mac[nt], 0, 0, 0);
        }
    }
    #pragma unroll
    for (int nt = 0; nt < 4; ++nt)
        #pragma unroll
        for (int i = 0; i < 4; ++i)
            Mw[(q*4 + i)*72 + nt*16 + l16] = f2b(mac[nt][i]);

    // ================= gate: wt = tanh(silu(M @ P1 + pb1) @ P2 + pb2) ========
    float4v gac[4];
    #pragma unroll
    for (int nt = 0; nt < 4; ++nt) {
        float bv = pb1[nt*16 + l16];
        gac[nt] = (float4v){bv, bv, bv, bv};
    }
    #pragma unroll
    for (int kk = 0; kk < 2; ++kk) {
        short8 a = *(const short8*)&Mw[l16*72 + kk*32 + q*8];
        #pragma unroll
        for (int nt = 0; nt < 4; ++nt) {
            short8 bf = *(const short8*)&wbuf[P1S_OFF + (((kk*4 + nt)*64) + lane) * 8];
            gac[nt] = __builtin_amdgcn_mfma_f32_16x16x32_bf16(a, bf, gac[nt], 0, 0, 0);
        }
    }
    float p2v[4];
    #pragma unroll
    for (int nt = 0; nt < 4; ++nt) p2v[nt] = P2[nt*16 + l16];
    const float pb2v = pb2[0];

    #pragma unroll
    for (int i = 0; i < 4; ++i) {
        float p = 0.f;
        #pragma unroll
        for (int nt = 0; nt < 4; ++nt) p += silu_(gac[nt][i]) * p2v[nt];
        p += __shfl_xor(p, 8);
        p += __shfl_xor(p, 4);
        p += __shfl_xor(p, 2);
        p += __shfl_xor(p, 1);
        float wt = tanh_fast_(p + pb2v);
        // park wt in spare fp32-aligned columns 64..65 of the message row
        if (l16 == 0) *(float*)&Mw[(q*4 + i)*72 + 64] = wt;
    }

    float* aggB = aggf + (size_t)b * C_ * 64;
    float* opB  = out_pos + (size_t)b * C_ * 3;

    // ================= in-wave segmented aggregation =========================
    float mrow[16];
    #pragma unroll
    for (int rr = 0; rr < 16; ++rr) mrow[rr] = b2f(Mw[rr*72 + lane]);
    float wtl = *(const float*)&Mw[l16*72 + 64];   // lane l16 = row l16's wt

    int dprev = __shfl(d_l, w16);
    float colacc = 0.f, pxa = 0.f, pya = 0.f, pza = 0.f;
    #pragma unroll
    for (int rr = 0; rr < 16; ++rr) {
        int dcur = __shfl(d_l, w16 + rr);          // wave-uniform
        if (dcur != dprev) {                       // uniform branch
            atomicAdd(&aggB[(size_t)dprev * 64 + lane], colacc);
            if (lane < 3) {
                float v = (lane == 0) ? pxa : (lane == 1) ? pya : pza;
                atomicAdd(&opB[(size_t)dprev * 3 + lane], v);
            }
            colacc = 0.f; pxa = 0.f; pya = 0.f; pza = 0.f;
            dprev = dcur;
        }
        float wt = __shfl(wtl, rr);
        colacc += mrow[rr];
        pxa = fmaf(wt, __shfl(relx, rr), pxa);
        pya = fmaf(wt, __shfl(rely, rr), pya);
        pza = fmaf(wt, __shfl(relz, rr), pza);
    }
    atomicAdd(&aggB[(size_t)dprev * 64 + lane], colacc);
    if (lane < 3) {
        float v = (lane == 0) ? pxa : (lane == 1) ? pya : pza;
        atomicAdd(&opB[(size_t)dprev * 3 + lane], v);
    }
}

// ---------------------------------------------------------------------------
// Node update via MFMA, barrier-free wave-private strips.
// ---------------------------------------------------------------------------
__global__ __launch_bounds__(256) void node_kernel(
    const float* __restrict__ feat, const unsigned short* __restrict__ featb,
    const float* __restrict__ aggf, const float* __restrict__ deg,
    const unsigned short* __restrict__ wbuf,
    const float* __restrict__ ub1, const float* __restrict__ ub2,
    float* __restrict__ out_feat)
{
    __shared__ unsigned short lds[4 * 3328];

    const int tid  = threadIdx.x;
    const int w    = tid >> 6;
    const int lane = tid & 63;
    const int q    = lane >> 4;
    const int l16  = lane & 15;
    const int g0   = blockIdx.x * 64;

    unsigned short* Xw = lds + w * 3328;
    unsigned short* Hw = Xw + 2176;

    const int rr4 = lane >> 4, c4 = lane & 15;
    #pragma unroll
    for (int it = 0; it < 4; ++it) {
        int rloc = it * 4 + rr4;
        int g = g0 + w*16 + rloc;
        int gc = (g >= C_) ? g - C_ : g;
        float sc = 1.f / fmaxf(deg[gc], 1.f);
        uint2  vf = *(const uint2*)&featb[(size_t)g * 64 + c4 * 4];
        float4 va = *(const float4*)&aggf[(size_t)g * 64 + c4 * 4];
        *(uint2*)&Xw[rloc*136 + c4*4]      = vf;
        *(uint2*)&Xw[rloc*136 + 64 + c4*4] =
            make_uint2(pk2u(va.x*sc, va.y*sc), pk2u(va.z*sc, va.w*sc));
    }

    float4v acc[4];
    #pragma unroll
    for (int nt = 0; nt < 4; ++nt) {
        float bv = ub1[nt*16 + l16];
        acc[nt] = (float4v){bv, bv, bv, bv};
    }
    #pragma unroll
    for (int kk = 0; kk < 4; ++kk) {
        short8 a = *(const short8*)&Xw[l16*136 + kk*32 + q*8];
        #pragma unroll
        for (int nt = 0; nt < 4; ++nt) {
            short8 bf = *(const short8*)&wbuf[U1S_OFF + (((kk*4 + nt)*64) + lane) * 8];
            acc[nt] = __builtin_amdgcn_mfma_f32_16x16x32_bf16(a, bf, acc[nt], 0, 0, 0);
        }
    }
    #pragma unroll
    for (int nt = 0; nt < 4; ++nt)
        #pragma unroll
        for (int i = 0; i < 4; ++i)
            Hw[(q*4 + i)*72 + nt*16 + l16] = f2b(silu_(acc[nt][i]));

    float4v oac[4];
    #pragma unroll
    for (int nt = 0; nt < 4; ++nt) {
        float bv = ub2[nt*16 + l16];
        oac[nt] = (float4v){bv, bv, bv, bv};
    }
    #pragma unroll
    for (int kk = 0; kk < 2; ++kk) {
        short8 a = *(const short8*)&Hw[l16*72 + kk*32 + q*8];
        #pragma unroll
        for (int nt = 0; nt < 4; ++nt) {
            short8 bf = *(const short8*)&wbuf[U2S_OFF + (((kk*4 + nt)*64) + lane) * 8];
            oac[nt] = __builtin_amdgcn_mfma_f32_16x16x32_bf16(a, bf, oac[nt], 0, 0, 0);
        }
    }
    #pragma unroll
    for (int nt = 0; nt < 4; ++nt)
        #pragma unroll
        for (int i = 0; i < 4; ++i) {
            size_t idx = (size_t)(g0 + w*16 + q*4 + i) * 64 + nt*16 + l16;
            out_feat[idx] = feat[idx] + oac[nt][i];
        }
}

extern "C" void kernel_launch(void* const* d_in, const int* in_sizes, int n_in,
                              void* d_out, int out_size, void* d_ws, size_t ws_size,
                              hipStream_t stream) {
    const float* feat = (const float*)d_in[0];
    const float* pos  = (const float*)d_in[1];
    const int*   ei   = (const int*)d_in[2];
    const float* deg  = (const float*)d_in[3];
    const int*   cni  = (const int*)d_in[4];
    const float* mask = (const float*)d_in[5];
    const float* W1   = (const float*)d_in[6];
    const float* b1   = (const float*)d_in[7];
    const float* W2   = (const float*)d_in[8];
    const float* b2   = (const float*)d_in[9];
    const float* P1   = (const float*)d_in[10];
    const float* pb1  = (const float*)d_in[11];
    const float* P2   = (const float*)d_in[12];
    const float* pb2  = (const float*)d_in[13];
    const float* U1   = (const float*)d_in[14];
    const float* ub1  = (const float*)d_in[15];
    const float* U2   = (const float*)d_in[16];
    const float* ub2  = (const float*)d_in[17];

    float* out_feat = (float*)d_out;                       // B*C*H
    float* out_pos  = out_feat + (size_t)B_ * C_ * H_;     // B*C*P

    // workspace layout (~37 MB)
    float* desc = (float*)d_ws;                                  // B*C*40 fp32
    float* aggf = desc + (size_t)B_ * C_ * 40;                   // B*C*64 fp32
    unsigned short* featb = (unsigned short*)(aggf + (size_t)B_ * C_ * 64); // B*C*64
    unsigned short* wbuf  = featb + (size_t)B_ * C_ * 64;        // 28672
    int* cnt    = (int*)(wbuf + WBUF_ELEMS);                     // C
    int* total  = cnt + C_;                                      // 4 (16B pad)
    int* cursor = total + 4;                                     // C
    int2* sedge = (int2*)(cursor + C_);                          // E int2
    float* inv8 = (float*)(sedge + E_);                          // B*E*8 fp32

    hipMemsetAsync(cnt, 0, (C_ + 4) * sizeof(int), stream);      // cnt + total

    combo_kernel<<<NB_COMBO, 256, 0, stream>>>(
        W1, W2, P1, U1, U2, wbuf, feat, featb, pos, cni, mask, desc, ei, cnt);

    alloc_kernel<<<(C_ + 255) / 256, 256, 0, stream>>>(cnt, cursor, total);
    scatter_kernel<<<(E_ + 255) / 256, 256, 0, stream>>>(ei, cursor, sedge);

    geom_kernel<<<NB_GEOMK, 256, 0, stream>>>(sedge, desc, inv8, aggf, pos, out_pos);

    edge_kernel<<<B_ * ET_, 256, 0, stream>>>(
        featb, sedge, inv8, wbuf, W1, b1, b2, pb1, P2, pb2, aggf, out_pos);

    node_kernel<<<(B_ * C_) / 64, 256, 0, stream>>>(
        feat, featb, aggf, deg, wbuf, ub1, ub2, out_feat);
}

// Round 10
// 232.886 us; speedup vs baseline: 1.4222x; 1.0617x over previous
//
#include <hip/hip_runtime.h>
#include <hip/hip_bf16.h>

#define B_ 2
#define C_ 20000
#define H_ 64
#define M_ 8
#define E_ 200000
#define P_ 3
#define EPS_ 1e-12f
#define ET_ (E_ / 64)   // edge tiles per batch = 3125

typedef __attribute__((ext_vector_type(8))) short short8;
typedef __attribute__((ext_vector_type(4))) float float4v;

__device__ __forceinline__ float silu_(float x) {
    return x / (1.f + __expf(-x));
}
__device__ __forceinline__ float tanh_fast_(float x) {
    float ex = __expf(2.f * x);
    return 1.f - 2.f / (ex + 1.f);
}
__device__ __forceinline__ unsigned short f2b(float f) {
    unsigned u = __float_as_uint(f);
    unsigned r = (u + 0x7FFF + ((u >> 16) & 1)) >> 16;   // RNE fp32->bf16
    return (unsigned short)r;
}
__device__ __forceinline__ float b2f(unsigned short h) {
    return __uint_as_float(((unsigned)h) << 16);
}
__device__ __forceinline__ unsigned pk2u(float a, float b) {
    __hip_bfloat162 h = __float22bfloat162_rn(make_float2(a, b)); // v_cvt_pk_bf16_f32
    unsigned u; __builtin_memcpy(&u, &h, sizeof(u)); return u;
}
// unpack 4 bf16 (8B) -> float4
__device__ __forceinline__ float4 up4_(const unsigned short* p) {
    uint2 u = *(const uint2*)p;
    return make_float4(__uint_as_float(u.x << 16),
                       __uint_as_float(u.x & 0xffff0000u),
                       __uint_as_float(u.y << 16),
                       __uint_as_float(u.y & 0xffff0000u));
}

// bf16 B-fragment-swizzled weights (K multiples of 32; W1 rows 128..131 on VALU)
#define W1S_OFF 0
#define W2S_OFF 8192
#define P1S_OFF 12288
#define U1S_OFF 16384
#define U2S_OFF 24576
#define WBUF_ELEMS 28672

// combo_kernel block ranges (all parts independent)
#define NB_PREP   120                    // 28672 weight-frag elems
#define NB_FEATB  2500                   // B*C*64/4 = 640000 threads
#define NB_DESC   157                    // ceil(B*C/256)
#define NB_HIST   782                    // ceil(E/256)
#define NB_COMBO  (NB_PREP + NB_FEATB + NB_DESC + NB_HIST)

// geom_kernel block ranges
#define NB_GEOM   6250                   // B*E/64 edges, 4 waves x 16 edges/block
#define NB_AGGZ   2500                   // zero aggf: B*C*64/4 float4
#define NB_PCPY   118                    // out_pos = pos: 30000 float4
#define NB_GEOMK  (NB_GEOM + NB_AGGZ + NB_PCPY)

__global__ __launch_bounds__(256) void combo_kernel(
    const float* __restrict__ W1, const float* __restrict__ W2,
    const float* __restrict__ P1, const float* __restrict__ U1,
    const float* __restrict__ U2, unsigned short* __restrict__ wbuf,
    const float* __restrict__ feat, unsigned short* __restrict__ featb,
    const float* __restrict__ pos, const int* __restrict__ cni,
    const float* __restrict__ mask, unsigned short* __restrict__ descb,
    const int* __restrict__ ei, int* __restrict__ cnt)
{
    const int bid = blockIdx.x;
    if (bid < NB_PREP) {
        // ---- weight swizzle -> bf16 B-fragments
        int t = bid * 256 + threadIdx.x;
        if (t >= WBUF_ELEMS) return;
        const float* W; int e;
        if (t < W2S_OFF)      { W = W1; e = t; }
        else if (t < U1S_OFF) { W = (t < P1S_OFF) ? W2 : P1; e = (t < P1S_OFF) ? t - W2S_OFF : t - P1S_OFF; }
        else if (t < U2S_OFF) { W = U1; e = t - U1S_OFF; }
        else                  { W = U2; e = t - U2S_OFF; }
        int j = e & 7, lane = (e >> 3) & 63, nt = (e >> 9) & 3, kk = e >> 11;
        int k = kk * 32 + ((lane >> 4) * 8) + j;
        int n = nt * 16 + (lane & 15);
        wbuf[t] = f2b(W[k * 64 + n]);
    } else if (bid < NB_PREP + NB_FEATB) {
        // ---- features -> bf16 cache (coalesced)
        int t = (bid - NB_PREP) * 256 + threadIdx.x;   // < 640000 exactly
        float4 v = *(const float4*)&feat[(size_t)t * 4];
        *(uint2*)&featb[(size_t)t * 4] = make_uint2(pk2u(v.x, v.y), pk2u(v.z, v.w));
    } else if (bid < NB_PREP + NB_FEATB + NB_DESC) {
        // ---- per-(b,cell) bf16 descriptor: 8x(x,y,z,m) + (centroid,msum) + own pos
        // 40 ushorts = 80B/record -> descb total 3.2MB, fits per-XCD L2.
        int tid = (bid - NB_PREP - NB_FEATB) * 256 + threadIdx.x;
        if (tid >= B_ * C_) return;
        int b = tid / C_, c = tid - b * C_;
        const float* pb = pos + (size_t)b * C_ * P_;
        unsigned short* R = descb + (size_t)tid * 40;
        int4 n0 = *(const int4*)&cni[c*8];
        int4 n1 = *(const int4*)&cni[c*8 + 4];
        float4 m0 = *(const float4*)&mask[c*8];
        float4 m1 = *(const float4*)&mask[c*8 + 4];
        int ni[8] = {n0.x, n0.y, n0.z, n0.w, n1.x, n1.y, n1.z, n1.w};
        float mm[8] = {m0.x, m0.y, m0.z, m0.w, m1.x, m1.y, m1.z, m1.w};
        float sx = 0.f, sy = 0.f, sz = 0.f, sm = 0.f;
        #pragma unroll
        for (int m = 0; m < 8; ++m) {
            float x = pb[ni[m]*3+0], y = pb[ni[m]*3+1], z = pb[ni[m]*3+2];
            *(uint2*)&R[m*4] = make_uint2(pk2u(x, y), pk2u(z, mm[m]));
            sx += x * mm[m]; sy += y * mm[m]; sz += z * mm[m]; sm += mm[m];
        }
        float inv = 1.f / fmaxf(sm, EPS_);
        *(uint2*)&R[32] = make_uint2(pk2u(sx*inv, sy*inv), pk2u(sz*inv, sm));
        *(uint2*)&R[36] = make_uint2(pk2u(pb[c*3+0], pb[c*3+1]), pk2u(pb[c*3+2], 0.f));
    } else {
        // ---- dst histogram
        int e = (bid - NB_PREP - NB_FEATB - NB_DESC) * 256 + threadIdx.x;
        if (e >= E_) return;
        atomicAdd(&cnt[ei[E_ + e]], 1);
    }
}

// ---------------------------------------------------------------------------
// alloc: wave-scan + one atomic bump per wave -> cursor (segment order free)
// ---------------------------------------------------------------------------
__global__ __launch_bounds__(256) void alloc_kernel(
    const int* __restrict__ cnt, int* __restrict__ cursor, int* __restrict__ total)
{
    int idx = blockIdx.x * 256 + threadIdx.x;
    int lane = threadIdx.x & 63;
    int v = (idx < C_) ? cnt[idx] : 0;
    int inc = v;
    #pragma unroll
    for (int s = 1; s < 64; s <<= 1) {
        int n = __shfl_up(inc, s);
        if (lane >= s) inc += n;
    }
    int wtot = __shfl(inc, 63);
    int base = 0;
    if (lane == 0) base = atomicAdd(total, wtot);
    base = __shfl(base, 0);
    if (idx < C_) cursor[idx] = base + inc - v;
}

__global__ __launch_bounds__(256) void scatter_kernel(
    const int* __restrict__ ei, int* __restrict__ cursor,
    int2* __restrict__ sedge)
{
    int e = blockIdx.x * 256 + threadIdx.x;
    if (e >= E_) return;
    int s = ei[e], d = ei[E_ + e];
    int slot = atomicAdd(&cursor[d], 1);
    sedge[slot] = make_int2(s, d);
}

// ---------------------------------------------------------------------------
// geom: quad-split geometry (R6-proven gather pattern). Wave = 16 edges;
// lane (l16,q) owns edge w*16+l16, quad q handles j-columns {2q, 2q+1};
// shfl_xor(16/32) butterflies combine partials. Descriptor gathers touch
// 32 distinct 80B bf16 records/wave -> L2-resident (descb = 3.2MB total).
// Also absorbs aggf-zero and out_pos=pos block ranges.
// ---------------------------------------------------------------------------
__global__ __launch_bounds__(256) void geom_kernel(
    const int2* __restrict__ sedge, const unsigned short* __restrict__ descb,
    float* __restrict__ inv8,
    float* __restrict__ aggf, const float* __restrict__ pos,
    float* __restrict__ out_pos)
{
    const int bid = blockIdx.x;
    if (bid >= NB_GEOM) {
        if (bid < NB_GEOM + NB_AGGZ) {
            int t = (bid - NB_GEOM) * 256 + threadIdx.x;
            ((float4*)aggf)[t] = make_float4(0.f, 0.f, 0.f, 0.f);
        } else {
            int t = (bid - NB_GEOM - NB_AGGZ) * 256 + threadIdx.x;
            if (t < (B_ * C_ * P_) / 4)
                ((float4*)out_pos)[t] = ((const float4*)pos)[t];
        }
        return;
    }
    const int tid  = threadIdx.x;
    const int w    = tid >> 6;
    const int lane = tid & 63;
    const int q    = lane >> 4;
    const int l16  = lane & 15;

    const int ge = bid * 64 + w * 16 + l16;     // global edge id < B*E
    const int b  = ge / E_;
    const int i  = ge - b * E_;                 // sorted-domain index
    const int2 sd = sedge[i];
    const unsigned short* Sb = descb + ((size_t)b * C_ + sd.x) * 40;
    const unsigned short* Db = descb + ((size_t)b * C_ + sd.y) * 40;

    const float INFV = __builtin_inff();
    float4 S[8];
    float a_i[8], infm_i[8], rowmin[8];
    #pragma unroll
    for (int k = 0; k < 8; ++k) {
        S[k] = up4_(&Sb[k*4]);
        a_i[k] = S[k].x*S[k].x + S[k].y*S[k].y + S[k].z*S[k].z + EPS_;
        infm_i[k] = (S[k].w > 0.f) ? 0.f : INFV;
        rowmin[k] = INFV;
    }
    float pair = 0.f, hyx = 0.f;
    #pragma unroll
    for (int jj = 0; jj < 2; ++jj) {
        float4 Dj = up4_(&Db[(q*2 + jj)*4]);
        float dp2 = Dj.x*Dj.x + Dj.y*Dj.y + Dj.z*Dj.z;
        float infm_j = (Dj.w > 0.f) ? 0.f : INFV;
        float colmin = INFV, psum = 0.f;
        #pragma unroll
        for (int k = 0; k < 8; ++k) {
            float cr = S[k].x*Dj.x + S[k].y*Dj.y + S[k].z*Dj.z;
            float t  = (a_i[k] + dp2) - 2.f*cr;
            float dd = sqrtf(fmaxf(t, EPS_));
            psum = fmaf(dd, S[k].w, psum);
            rowmin[k] = fminf(rowmin[k], dd + infm_j);
            colmin    = fminf(colmin,    dd + infm_i[k]);
        }
        pair = fmaf(Dj.w, psum, pair);
        hyx = fmaxf(hyx, (Dj.w > 0.f) ? colmin : 0.f);
    }
    // combine quad partials (lanes l16, l16+16, l16+32, l16+48)
    pair += __shfl_xor(pair, 16);  pair += __shfl_xor(pair, 32);
    hyx = fmaxf(hyx, __shfl_xor(hyx, 16));  hyx = fmaxf(hyx, __shfl_xor(hyx, 32));
    #pragma unroll
    for (int k = 0; k < 8; ++k) {
        rowmin[k] = fminf(rowmin[k], __shfl_xor(rowmin[k], 16));
        rowmin[k] = fminf(rowmin[k], __shfl_xor(rowmin[k], 32));
    }
    float hxy = 0.f;
    #pragma unroll
    for (int k = 0; k < 8; ++k)
        hxy = fmaxf(hxy, (S[k].w > 0.f) ? rowmin[k] : 0.f);

    float4 Sc = up4_(&Sb[32]), Dc = up4_(&Db[32]);
    float cdx = Sc.x - Dc.x, cdy = Sc.y - Dc.y, cdz = Sc.z - Dc.z;
    float4 Sp = up4_(&Sb[36]), Dp = up4_(&Db[36]);
    float relx = Sp.x - Dp.x, rely = Sp.y - Dp.y, relz = Sp.z - Dp.z;
    float dist = sqrtf(relx*relx + rely*rely + relz*relz);
    float cen  = sqrtf(cdx*cdx + cdy*cdy + cdz*cdz);
    float haus = fmaxf(hxy, hyx);

    size_t off = ((size_t)b * E_ + i) * 8;
    if (q == 0)      *(float4*)&inv8[off]     = make_float4(dist, pair, cen, haus);
    else if (q == 1) *(float4*)&inv8[off + 4] = make_float4(relx, rely, relz, 0.f);
}

// ---------------------------------------------------------------------------
// Edge kernel: 3 MFMA MLP stages + in-wave segmented aggregation.
// 4 independent waves/block, barrier-free wave-private LDS arenas;
// invariants read from inv8 (quad-broadcast loads).
// ---------------------------------------------------------------------------
__global__ __launch_bounds__(256) void edge_kernel(
    const unsigned short* __restrict__ featb,
    const int2* __restrict__ sedge, const float* __restrict__ inv8,
    const unsigned short* __restrict__ wbuf, const float* __restrict__ W1,
    const float* __restrict__ b1, const float* __restrict__ b2,
    const float* __restrict__ pb1, const float* __restrict__ P2,
    const float* __restrict__ pb2,
    float* __restrict__ aggf, float* __restrict__ out_pos)
{
    __shared__ unsigned short lds[4 * 3328];   // 26624 B

    const int tid  = threadIdx.x;
    const int w    = tid >> 6;
    const int lane = tid & 63;
    const int q    = lane >> 4;
    const int l16  = lane & 15;
    const int w16  = w * 16;

    const int tile = blockIdx.x;
    const int b    = tile / ET_;
    const int i0   = (tile - b * ET_) * 64;
    const int2 sd  = sedge[i0 + lane];
    const int s_l  = sd.x;
    const int d_l  = sd.y;
    const unsigned short* fb = featb + (size_t)b * C_ * H_;
    const float* ivb = inv8 + ((size_t)b * E_ + i0) * 8;

    unsigned short* Xw = lds + w * 3328;
    unsigned short* Hw = Xw + 2176;
    unsigned short* Mw = Xw;   // alias: X dead before M written (dep chain)

    // per-lane rel for edge w16+l16 (16 distinct addrs, quad-duplicated)
    float4 ivhi = *(const float4*)&ivb[(w16 + l16) * 8 + 4];
    const float relx = ivhi.x, rely = ivhi.y, relz = ivhi.z;

    // ================= stage X = [h_src | h_dst] from bf16 cache =============
    const int rr4 = lane >> 4, c4 = lane & 15;
    #pragma unroll
    for (int it = 0; it < 4; ++it) {
        int rloc = it * 4 + rr4;
        int r = w16 + rloc;
        int sr = __shfl(s_l, r);
        int dr = __shfl(d_l, r);
        uint2 vs = *(const uint2*)&fb[(size_t)sr * 64 + c4 * 4];
        uint2 vd = *(const uint2*)&fb[(size_t)dr * 64 + c4 * 4];
        *(uint2*)&Xw[rloc*136 + c4*4]      = vs;
        *(uint2*)&Xw[rloc*136 + 64 + c4*4] = vd;
    }

    // ================= layer 1: MFMA k<128 + fp32 invariant tail =============
    float4v acc[4];
    #pragma unroll
    for (int nt = 0; nt < 4; ++nt) {
        float bv = b1[nt*16 + l16];
        acc[nt] = (float4v){bv, bv, bv, bv};
    }
    #pragma unroll
    for (int kk = 0; kk < 4; ++kk) {
        short8 a = *(const short8*)&Xw[l16*136 + kk*32 + q*8];
        #pragma unroll
        for (int nt = 0; nt < 4; ++nt) {
            short8 bf = *(const short8*)&wbuf[W1S_OFF + (((kk*4 + nt)*64) + lane) * 8];
            acc[nt] = __builtin_amdgcn_mfma_f32_16x16x32_bf16(a, bf, acc[nt], 0, 0, 0);
        }
    }
    float4 iv[4];
    #pragma unroll
    for (int i = 0; i < 4; ++i)
        iv[i] = *(const float4*)&ivb[(w16 + q*4 + i) * 8];   // quad-broadcast
    #pragma unroll
    for (int nt = 0; nt < 4; ++nt) {
        float wa = W1[128*64 + nt*16 + l16];
        float wb = W1[129*64 + nt*16 + l16];
        float wc = W1[130*64 + nt*16 + l16];
        float wd = W1[131*64 + nt*16 + l16];
        #pragma unroll
        for (int i = 0; i < 4; ++i)
            acc[nt][i] += iv[i].x*wa + iv[i].y*wb + iv[i].z*wc + iv[i].w*wd;
    }
    #pragma unroll
    for (int nt = 0; nt < 4; ++nt)
        #pragma unroll
        for (int i = 0; i < 4; ++i)
            Hw[(q*4 + i)*72 + nt*16 + l16] = f2b(silu_(acc[nt][i]));

    // ================= layer 2 -> messages ===================================
    float4v mac[4];
    #pragma unroll
    for (int nt = 0; nt < 4; ++nt) {
        float bv = b2[nt*16 + l16];
        mac[nt] = (float4v){bv, bv, bv, bv};
    }
    #pragma unroll
    for (int kk = 0; kk < 2; ++kk) {
        short8 a = *(const short8*)&Hw[l16*72 + kk*32 + q*8];
        #pragma unroll
        for (int nt = 0; nt < 4; ++nt) {
            short8 bf = *(const short8*)&wbuf[W2S_OFF + (((kk*4 + nt)*64) + lane) * 8];
            mac[nt] = __builtin_amdgcn_mfma_f32_16x16x32_bf16(a, bf, mac[nt], 0, 0, 0);
        }
    }
    #pragma unroll
    for (int nt = 0; nt < 4; ++nt)
        #pragma unroll
        for (int i = 0; i < 4; ++i)
            Mw[(q*4 + i)*72 + nt*16 + l16] = f2b(mac[nt][i]);

    // ================= gate: wt = tanh(silu(M @ P1 + pb1) @ P2 + pb2) ========
    float4v gac[4];
    #pragma unroll
    for (int nt = 0; nt < 4; ++nt) {
        float bv = pb1[nt*16 + l16];
        gac[nt] = (float4v){bv, bv, bv, bv};
    }
    #pragma unroll
    for (int kk = 0; kk < 2; ++kk) {
        short8 a = *(const short8*)&Mw[l16*72 + kk*32 + q*8];
        #pragma unroll
        for (int nt = 0; nt < 4; ++nt) {
            short8 bf = *(const short8*)&wbuf[P1S_OFF + (((kk*4 + nt)*64) + lane) * 8];
            gac[nt] = __builtin_amdgcn_mfma_f32_16x16x32_bf16(a, bf, gac[nt], 0, 0, 0);
        }
    }
    float p2v[4];
    #pragma unroll
    for (int nt = 0; nt < 4; ++nt) p2v[nt] = P2[nt*16 + l16];
    const float pb2v = pb2[0];

    #pragma unroll
    for (int i = 0; i < 4; ++i) {
        float p = 0.f;
        #pragma unroll
        for (int nt = 0; nt < 4; ++nt) p += silu_(gac[nt][i]) * p2v[nt];
        p += __shfl_xor(p, 8);
        p += __shfl_xor(p, 4);
        p += __shfl_xor(p, 2);
        p += __shfl_xor(p, 1);
        float wt = tanh_fast_(p + pb2v);
        // park wt in spare fp32-aligned columns 64..65 of the message row
        if (l16 == 0) *(float*)&Mw[(q*4 + i)*72 + 64] = wt;
    }

    float* aggB = aggf + (size_t)b * C_ * 64;
    float* opB  = out_pos + (size_t)b * C_ * 3;

    // ================= in-wave segmented aggregation =========================
    float mrow[16];
    #pragma unroll
    for (int rr = 0; rr < 16; ++rr) mrow[rr] = b2f(Mw[rr*72 + lane]);
    float wtl = *(const float*)&Mw[l16*72 + 64];   // lane l16 = row l16's wt

    int dprev = __shfl(d_l, w16);
    float colacc = 0.f, pxa = 0.f, pya = 0.f, pza = 0.f;
    #pragma unroll
    for (int rr = 0; rr < 16; ++rr) {
        int dcur = __shfl(d_l, w16 + rr);          // wave-uniform
        if (dcur != dprev) {                       // uniform branch
            atomicAdd(&aggB[(size_t)dprev * 64 + lane], colacc);
            if (lane < 3) {
                float v = (lane == 0) ? pxa : (lane == 1) ? pya : pza;
                atomicAdd(&opB[(size_t)dprev * 3 + lane], v);
            }
            colacc = 0.f; pxa = 0.f; pya = 0.f; pza = 0.f;
            dprev = dcur;
        }
        float wt = __shfl(wtl, rr);
        colacc += mrow[rr];
        pxa = fmaf(wt, __shfl(relx, rr), pxa);
        pya = fmaf(wt, __shfl(rely, rr), pya);
        pza = fmaf(wt, __shfl(relz, rr), pza);
    }
    atomicAdd(&aggB[(size_t)dprev * 64 + lane], colacc);
    if (lane < 3) {
        float v = (lane == 0) ? pxa : (lane == 1) ? pya : pza;
        atomicAdd(&opB[(size_t)dprev * 3 + lane], v);
    }
}

// ---------------------------------------------------------------------------
// Node update via MFMA, barrier-free wave-private strips.
// ---------------------------------------------------------------------------
__global__ __launch_bounds__(256) void node_kernel(
    const float* __restrict__ feat, const unsigned short* __restrict__ featb,
    const float* __restrict__ aggf, const float* __restrict__ deg,
    const unsigned short* __restrict__ wbuf,
    const float* __restrict__ ub1, const float* __restrict__ ub2,
    float* __restrict__ out_feat)
{
    __shared__ unsigned short lds[4 * 3328];

    const int tid  = threadIdx.x;
    const int w    = tid >> 6;
    const int lane = tid & 63;
    const int q    = lane >> 4;
    const int l16  = lane & 15;
    const int g0   = blockIdx.x * 64;

    unsigned short* Xw = lds + w * 3328;
    unsigned short* Hw = Xw + 2176;

    const int rr4 = lane >> 4, c4 = lane & 15;
    #pragma unroll
    for (int it = 0; it < 4; ++it) {
        int rloc = it * 4 + rr4;
        int g = g0 + w*16 + rloc;
        int gc = (g >= C_) ? g - C_ : g;
        float sc = 1.f / fmaxf(deg[gc], 1.f);
        uint2  vf = *(const uint2*)&featb[(size_t)g * 64 + c4 * 4];
        float4 va = *(const float4*)&aggf[(size_t)g * 64 + c4 * 4];
        *(uint2*)&Xw[rloc*136 + c4*4]      = vf;
        *(uint2*)&Xw[rloc*136 + 64 + c4*4] =
            make_uint2(pk2u(va.x*sc, va.y*sc), pk2u(va.z*sc, va.w*sc));
    }

    float4v acc[4];
    #pragma unroll
    for (int nt = 0; nt < 4; ++nt) {
        float bv = ub1[nt*16 + l16];
        acc[nt] = (float4v){bv, bv, bv, bv};
    }
    #pragma unroll
    for (int kk = 0; kk < 4; ++kk) {
        short8 a = *(const short8*)&Xw[l16*136 + kk*32 + q*8];
        #pragma unroll
        for (int nt = 0; nt < 4; ++nt) {
            short8 bf = *(const short8*)&wbuf[U1S_OFF + (((kk*4 + nt)*64) + lane) * 8];
            acc[nt] = __builtin_amdgcn_mfma_f32_16x16x32_bf16(a, bf, acc[nt], 0, 0, 0);
        }
    }
    #pragma unroll
    for (int nt = 0; nt < 4; ++nt)
        #pragma unroll
        for (int i = 0; i < 4; ++i)
            Hw[(q*4 + i)*72 + nt*16 + l16] = f2b(silu_(acc[nt][i]));

    float4v oac[4];
    #pragma unroll
    for (int nt = 0; nt < 4; ++nt) {
        float bv = ub2[nt*16 + l16];
        oac[nt] = (float4v){bv, bv, bv, bv};
    }
    #pragma unroll
    for (int kk = 0; kk < 2; ++kk) {
        short8 a = *(const short8*)&Hw[l16*72 + kk*32 + q*8];
        #pragma unroll
        for (int nt = 0; nt < 4; ++nt) {
            short8 bf = *(const short8*)&wbuf[U2S_OFF + (((kk*4 + nt)*64) + lane) * 8];
            oac[nt] = __builtin_amdgcn_mfma_f32_16x16x32_bf16(a, bf, oac[nt], 0, 0, 0);
        }
    }
    #pragma unroll
    for (int nt = 0; nt < 4; ++nt)
        #pragma unroll
        for (int i = 0; i < 4; ++i) {
            size_t idx = (size_t)(g0 + w*16 + q*4 + i) * 64 + nt*16 + l16;
            out_feat[idx] = feat[idx] + oac[nt][i];
        }
}

extern "C" void kernel_launch(void* const* d_in, const int* in_sizes, int n_in,
                              void* d_out, int out_size, void* d_ws, size_t ws_size,
                              hipStream_t stream) {
    const float* feat = (const float*)d_in[0];
    const float* pos  = (const float*)d_in[1];
    const int*   ei   = (const int*)d_in[2];
    const float* deg  = (const float*)d_in[3];
    const int*   cni  = (const int*)d_in[4];
    const float* mask = (const float*)d_in[5];
    const float* W1   = (const float*)d_in[6];
    const float* b1   = (const float*)d_in[7];
    const float* W2   = (const float*)d_in[8];
    const float* b2   = (const float*)d_in[9];
    const float* P1   = (const float*)d_in[10];
    const float* pb1  = (const float*)d_in[11];
    const float* P2   = (const float*)d_in[12];
    const float* pb2  = (const float*)d_in[13];
    const float* U1   = (const float*)d_in[14];
    const float* ub1  = (const float*)d_in[15];
    const float* U2   = (const float*)d_in[16];
    const float* ub2  = (const float*)d_in[17];

    float* out_feat = (float*)d_out;                       // B*C*H
    float* out_pos  = out_feat + (size_t)B_ * C_ * H_;     // B*C*P

    // workspace layout (~34 MB)
    float* aggf = (float*)d_ws;                                  // B*C*64 fp32
    unsigned short* featb = (unsigned short*)(aggf + (size_t)B_ * C_ * 64); // B*C*64
    unsigned short* descb = featb + (size_t)B_ * C_ * 64;        // B*C*40 bf16
    unsigned short* wbuf  = descb + (size_t)B_ * C_ * 40;        // 28672
    int* cnt    = (int*)(wbuf + WBUF_ELEMS);                     // C
    int* total  = cnt + C_;                                      // 4 (pad)
    int* cursor = total + 4;                                     // C
    int2* sedge = (int2*)(cursor + C_);                          // E int2
    float* inv8 = (float*)(sedge + E_);                          // B*E*8 fp32

    hipMemsetAsync(cnt, 0, (C_ + 4) * sizeof(int), stream);      // cnt + total

    combo_kernel<<<NB_COMBO, 256, 0, stream>>>(
        W1, W2, P1, U1, U2, wbuf, feat, featb, pos, cni, mask, descb, ei, cnt);

    alloc_kernel<<<(C_ + 255) / 256, 256, 0, stream>>>(cnt, cursor, total);
    scatter_kernel<<<(E_ + 255) / 256, 256, 0, stream>>>(ei, cursor, sedge);

    geom_kernel<<<NB_GEOMK, 256, 0, stream>>>(sedge, descb, inv8, aggf, pos, out_pos);

    edge_kernel<<<B_ * ET_, 256, 0, stream>>>(
        featb, sedge, inv8, wbuf, W1, b1, b2, pb1, P2, pb2, aggf, out_pos);

    node_kernel<<<(B_ * C_) / 64, 256, 0, stream>>>(
        feat, featb, aggf, deg, wbuf, ub1, ub2, out_feat);
}

// Round 11
// 228.974 us; speedup vs baseline: 1.4465x; 1.0171x over previous
//
#include <hip/hip_runtime.h>
#include <hip/hip_bf16.h>

#define B_ 2
#define C_ 20000
#define H_ 64
#define M_ 8
#define E_ 200000
#define P_ 3
#define EPS_ 1e-12f
#define ET_ (E_ / 64)   // edge tiles per batch = 3125

typedef __attribute__((ext_vector_type(8))) short short8;
typedef __attribute__((ext_vector_type(4))) float float4v;

__device__ __forceinline__ float silu_(float x) {
    return x / (1.f + __expf(-x));
}
__device__ __forceinline__ float tanh_fast_(float x) {
    float ex = __expf(2.f * x);
    return 1.f - 2.f / (ex + 1.f);
}
__device__ __forceinline__ unsigned short f2b(float f) {
    unsigned u = __float_as_uint(f);
    unsigned r = (u + 0x7FFF + ((u >> 16) & 1)) >> 16;   // RNE fp32->bf16
    return (unsigned short)r;
}
__device__ __forceinline__ float b2f(unsigned short h) {
    return __uint_as_float(((unsigned)h) << 16);
}
__device__ __forceinline__ unsigned pk2u(float a, float b) {
    __hip_bfloat162 h = __float22bfloat162_rn(make_float2(a, b)); // v_cvt_pk_bf16_f32
    unsigned u; __builtin_memcpy(&u, &h, sizeof(u)); return u;
}
// unpack 4 bf16 (8B) -> float4
__device__ __forceinline__ float4 up4_(const unsigned short* p) {
    uint2 u = *(const uint2*)p;
    return make_float4(__uint_as_float(u.x << 16),
                       __uint_as_float(u.x & 0xffff0000u),
                       __uint_as_float(u.y << 16),
                       __uint_as_float(u.y & 0xffff0000u));
}

// bf16 B-fragment-swizzled weights. W1 is K=160 (rows 128..131 = invariants,
// 132..159 zero); P1 slot holds W2@P1 (gate pre-association).
#define W1S_OFF 0
#define W2S_OFF 10240
#define P1S_OFF 14336
#define U1S_OFF 18432
#define U2S_OFF 26624
#define WBUF_ELEMS 30720

// combo_kernel block ranges (all parts independent)
#define NB_PREP   120                    // 30720 weight-frag elems
#define NB_FEATB  2500                   // B*C*64/4 = 640000 threads
#define NB_DESC   157                    // ceil(B*C/256)
#define NB_HIST   782                    // ceil(E/256)
#define NB_GB     1                      // gateb = b2@P1 + pb1
#define NB_COMBO  (NB_PREP + NB_FEATB + NB_DESC + NB_HIST + NB_GB)

// geom_kernel block ranges
#define NB_GEOM   6250                   // B*E/64 edges, 4 waves x 16 edges/block
#define NB_AGGZ   2500                   // zero aggf: B*C*64/4 float4
#define NB_PCPY   118                    // out_pos = pos: 30000 float4
#define NB_GEOMK  (NB_GEOM + NB_AGGZ + NB_PCPY)

__global__ __launch_bounds__(256) void combo_kernel(
    const float* __restrict__ W1, const float* __restrict__ W2,
    const float* __restrict__ P1, const float* __restrict__ U1,
    const float* __restrict__ U2, unsigned short* __restrict__ wbuf,
    const float* __restrict__ feat, unsigned short* __restrict__ featb,
    const float* __restrict__ pos, const int* __restrict__ cni,
    const float* __restrict__ mask, unsigned short* __restrict__ descb,
    const int* __restrict__ ei, int* __restrict__ cnt,
    const float* __restrict__ b2, const float* __restrict__ pb1,
    float* __restrict__ gateb)
{
    const int bid = blockIdx.x;
    if (bid < NB_PREP) {
        // ---- weight swizzle -> bf16 B-fragments
        int t = bid * 256 + threadIdx.x;
        if (t >= WBUF_ELEMS) return;
        int e;
        int j, lane, nt, kk, k, n;
        if (t < W2S_OFF) {
            // W1, K padded to 160: rows >=132 are zero (128..131 = invariant cols)
            e = t;
            j = e & 7; lane = (e >> 3) & 63; nt = (e >> 9) & 3; kk = e >> 11;
            k = kk * 32 + ((lane >> 4) * 8) + j;
            n = nt * 16 + (lane & 15);
            wbuf[t] = f2b((k < 132) ? W1[k * 64 + n] : 0.f);
        } else if (t < P1S_OFF) {
            e = t - W2S_OFF;
            j = e & 7; lane = (e >> 3) & 63; nt = (e >> 9) & 3; kk = e >> 11;
            k = kk * 32 + ((lane >> 4) * 8) + j;
            n = nt * 16 + (lane & 15);
            wbuf[t] = f2b(W2[k * 64 + n]);
        } else if (t < U1S_OFF) {
            // gate pre-association: element (k,n) of W2@P1
            e = t - P1S_OFF;
            j = e & 7; lane = (e >> 3) & 63; nt = (e >> 9) & 3; kk = e >> 11;
            k = kk * 32 + ((lane >> 4) * 8) + j;
            n = nt * 16 + (lane & 15);
            float acc = 0.f;
            for (int j2 = 0; j2 < 64; ++j2)
                acc = fmaf(W2[k * 64 + j2], P1[j2 * 64 + n], acc);
            wbuf[t] = f2b(acc);
        } else {
            const float* W = (t < U2S_OFF) ? U1 : U2;
            e = (t < U2S_OFF) ? t - U1S_OFF : t - U2S_OFF;
            j = e & 7; lane = (e >> 3) & 63; nt = (e >> 9) & 3; kk = e >> 11;
            k = kk * 32 + ((lane >> 4) * 8) + j;
            n = nt * 16 + (lane & 15);
            wbuf[t] = f2b(W[k * 64 + n]);
        }
    } else if (bid < NB_PREP + NB_FEATB) {
        // ---- features -> bf16 cache (coalesced)
        int t = (bid - NB_PREP) * 256 + threadIdx.x;   // < 640000 exactly
        float4 v = *(const float4*)&feat[(size_t)t * 4];
        *(uint2*)&featb[(size_t)t * 4] = make_uint2(pk2u(v.x, v.y), pk2u(v.z, v.w));
    } else if (bid < NB_PREP + NB_FEATB + NB_DESC) {
        // ---- per-(b,cell) bf16 descriptor: 8x(x,y,z,m) + (centroid,msum) + own pos
        int tid = (bid - NB_PREP - NB_FEATB) * 256 + threadIdx.x;
        if (tid >= B_ * C_) return;
        int b = tid / C_, c = tid - b * C_;
        const float* pb = pos + (size_t)b * C_ * P_;
        unsigned short* R = descb + (size_t)tid * 40;
        int4 n0 = *(const int4*)&cni[c*8];
        int4 n1 = *(const int4*)&cni[c*8 + 4];
        float4 m0 = *(const float4*)&mask[c*8];
        float4 m1 = *(const float4*)&mask[c*8 + 4];
        int ni[8] = {n0.x, n0.y, n0.z, n0.w, n1.x, n1.y, n1.z, n1.w};
        float mm[8] = {m0.x, m0.y, m0.z, m0.w, m1.x, m1.y, m1.z, m1.w};
        float sx = 0.f, sy = 0.f, sz = 0.f, sm = 0.f;
        #pragma unroll
        for (int m = 0; m < 8; ++m) {
            float x = pb[ni[m]*3+0], y = pb[ni[m]*3+1], z = pb[ni[m]*3+2];
            *(uint2*)&R[m*4] = make_uint2(pk2u(x, y), pk2u(z, mm[m]));
            sx += x * mm[m]; sy += y * mm[m]; sz += z * mm[m]; sm += mm[m];
        }
        float inv = 1.f / fmaxf(sm, EPS_);
        *(uint2*)&R[32] = make_uint2(pk2u(sx*inv, sy*inv), pk2u(sz*inv, sm));
        *(uint2*)&R[36] = make_uint2(pk2u(pb[c*3+0], pb[c*3+1]), pk2u(pb[c*3+2], 0.f));
    } else if (bid < NB_PREP + NB_FEATB + NB_DESC + NB_HIST) {
        // ---- dst histogram
        int e = (bid - NB_PREP - NB_FEATB - NB_DESC) * 256 + threadIdx.x;
        if (e >= E_) return;
        atomicAdd(&cnt[ei[E_ + e]], 1);
    } else {
        // ---- gateb[n] = sum_j b2[j]*P1[j][n] + pb1[n]
        int n = threadIdx.x;
        if (n >= 64) return;
        float acc = pb1[n];
        for (int j = 0; j < 64; ++j)
            acc = fmaf(b2[j], P1[j * 64 + n], acc);
        gateb[n] = acc;
    }
}

// ---------------------------------------------------------------------------
// alloc: wave-scan + one atomic bump per wave -> cursor (segment order free)
// ---------------------------------------------------------------------------
__global__ __launch_bounds__(256) void alloc_kernel(
    const int* __restrict__ cnt, int* __restrict__ cursor, int* __restrict__ total)
{
    int idx = blockIdx.x * 256 + threadIdx.x;
    int lane = threadIdx.x & 63;
    int v = (idx < C_) ? cnt[idx] : 0;
    int inc = v;
    #pragma unroll
    for (int s = 1; s < 64; s <<= 1) {
        int n = __shfl_up(inc, s);
        if (lane >= s) inc += n;
    }
    int wtot = __shfl(inc, 63);
    int base = 0;
    if (lane == 0) base = atomicAdd(total, wtot);
    base = __shfl(base, 0);
    if (idx < C_) cursor[idx] = base + inc - v;
}

__global__ __launch_bounds__(256) void scatter_kernel(
    const int* __restrict__ ei, int* __restrict__ cursor,
    int2* __restrict__ sedge)
{
    int e = blockIdx.x * 256 + threadIdx.x;
    if (e >= E_) return;
    int s = ei[e], d = ei[E_ + e];
    int slot = atomicAdd(&cursor[d], 1);
    sedge[slot] = make_int2(s, d);
}

// ---------------------------------------------------------------------------
// geom: quad-split geometry (L2-resident bf16 descriptors, 32 distinct
// 80B records/wave). Also absorbs aggf-zero and out_pos=pos block ranges.
// ---------------------------------------------------------------------------
__global__ __launch_bounds__(256) void geom_kernel(
    const int2* __restrict__ sedge, const unsigned short* __restrict__ descb,
    float* __restrict__ inv8,
    float* __restrict__ aggf, const float* __restrict__ pos,
    float* __restrict__ out_pos)
{
    const int bid = blockIdx.x;
    if (bid >= NB_GEOM) {
        if (bid < NB_GEOM + NB_AGGZ) {
            int t = (bid - NB_GEOM) * 256 + threadIdx.x;
            ((float4*)aggf)[t] = make_float4(0.f, 0.f, 0.f, 0.f);
        } else {
            int t = (bid - NB_GEOM - NB_AGGZ) * 256 + threadIdx.x;
            if (t < (B_ * C_ * P_) / 4)
                ((float4*)out_pos)[t] = ((const float4*)pos)[t];
        }
        return;
    }
    const int tid  = threadIdx.x;
    const int w    = tid >> 6;
    const int lane = tid & 63;
    const int q    = lane >> 4;
    const int l16  = lane & 15;

    const int ge = bid * 64 + w * 16 + l16;     // global edge id < B*E
    const int b  = ge / E_;
    const int i  = ge - b * E_;                 // sorted-domain index
    const int2 sd = sedge[i];
    const unsigned short* Sb = descb + ((size_t)b * C_ + sd.x) * 40;
    const unsigned short* Db = descb + ((size_t)b * C_ + sd.y) * 40;

    const float INFV = __builtin_inff();
    float4 S[8];
    float a_i[8], infm_i[8], rowmin[8];
    #pragma unroll
    for (int k = 0; k < 8; ++k) {
        S[k] = up4_(&Sb[k*4]);
        a_i[k] = S[k].x*S[k].x + S[k].y*S[k].y + S[k].z*S[k].z + EPS_;
        infm_i[k] = (S[k].w > 0.f) ? 0.f : INFV;
        rowmin[k] = INFV;
    }
    float pair = 0.f, hyx = 0.f;
    #pragma unroll
    for (int jj = 0; jj < 2; ++jj) {
        float4 Dj = up4_(&Db[(q*2 + jj)*4]);
        float dp2 = Dj.x*Dj.x + Dj.y*Dj.y + Dj.z*Dj.z;
        float infm_j = (Dj.w > 0.f) ? 0.f : INFV;
        float colmin = INFV, psum = 0.f;
        #pragma unroll
        for (int k = 0; k < 8; ++k) {
            float cr = S[k].x*Dj.x + S[k].y*Dj.y + S[k].z*Dj.z;
            float t  = (a_i[k] + dp2) - 2.f*cr;
            float dd = sqrtf(fmaxf(t, EPS_));
            psum = fmaf(dd, S[k].w, psum);
            rowmin[k] = fminf(rowmin[k], dd + infm_j);
            colmin    = fminf(colmin,    dd + infm_i[k]);
        }
        pair = fmaf(Dj.w, psum, pair);
        hyx = fmaxf(hyx, (Dj.w > 0.f) ? colmin : 0.f);
    }
    pair += __shfl_xor(pair, 16);  pair += __shfl_xor(pair, 32);
    hyx = fmaxf(hyx, __shfl_xor(hyx, 16));  hyx = fmaxf(hyx, __shfl_xor(hyx, 32));
    #pragma unroll
    for (int k = 0; k < 8; ++k) {
        rowmin[k] = fminf(rowmin[k], __shfl_xor(rowmin[k], 16));
        rowmin[k] = fminf(rowmin[k], __shfl_xor(rowmin[k], 32));
    }
    float hxy = 0.f;
    #pragma unroll
    for (int k = 0; k < 8; ++k)
        hxy = fmaxf(hxy, (S[k].w > 0.f) ? rowmin[k] : 0.f);

    float4 Sc = up4_(&Sb[32]), Dc = up4_(&Db[32]);
    float cdx = Sc.x - Dc.x, cdy = Sc.y - Dc.y, cdz = Sc.z - Dc.z;
    float4 Sp = up4_(&Sb[36]), Dp = up4_(&Db[36]);
    float relx = Sp.x - Dp.x, rely = Sp.y - Dp.y, relz = Sp.z - Dp.z;
    float dist = sqrtf(relx*relx + rely*rely + relz*relz);
    float cen  = sqrtf(cdx*cdx + cdy*cdy + cdz*cdz);
    float haus = fmaxf(hxy, hyx);

    size_t off = ((size_t)b * E_ + i) * 8;
    if (q == 0)      *(float4*)&inv8[off]     = make_float4(dist, pair, cen, haus);
    else if (q == 1) *(float4*)&inv8[off + 4] = make_float4(relx, rely, relz, 0.f);
}

// ---------------------------------------------------------------------------
// Edge kernel: MFMA MLPs with (1) invariants folded into K (K=160, no fp32
// tail), (2) gate = H @ (W2@P1) + gateb sharing layer-2 A-frags, fp32 M in
// LDS, (3) prefix-scan pos update. Barrier-free wave-private LDS.
// ---------------------------------------------------------------------------
__global__ __launch_bounds__(256) void edge_kernel(
    const unsigned short* __restrict__ featb,
    const int2* __restrict__ sedge, const float* __restrict__ inv8,
    const unsigned short* __restrict__ wbuf,
    const float* __restrict__ b1, const float* __restrict__ b2,
    const float* __restrict__ gateb, const float* __restrict__ P2,
    const float* __restrict__ pb2,
    float* __restrict__ aggf, float* __restrict__ out_pos)
{
    __shared__ unsigned short lds[4 * 3840];   // 30720 B -> 5 blocks/CU

    const int tid  = threadIdx.x;
    const int w    = tid >> 6;
    const int lane = tid & 63;
    const int q    = lane >> 4;
    const int l16  = lane & 15;
    const int w16  = w * 16;

    const int tile = blockIdx.x;
    const int b    = tile / ET_;
    const int i0   = (tile - b * ET_) * 64;
    const int2 sd  = sedge[i0 + lane];
    const int s_l  = sd.x;
    const int d_l  = sd.y;
    const unsigned short* fb = featb + (size_t)b * C_ * H_;
    const float* ivb = inv8 + ((size_t)b * E_ + i0) * 8;

    unsigned short* Xw = lds + w * 3840;   // X: 16 x 168 bf16 (K=160 + pad)
    unsigned short* Hw = Xw + 2688;        // H: 16 x 72 bf16
    float* Mw = (float*)Xw;                // M: 16 x 68 fp32, aliases X (dep chain)

    // per-lane rel for edge w16+l16 (row l16, duplicated across quads)
    float4 ivhi = *(const float4*)&ivb[(w16 + l16) * 8 + 4];
    const float relx = ivhi.x, rely = ivhi.y, relz = ivhi.z;

    // ================= stage X = [h_src | h_dst | iv4 | zeros] ==============
    const int rr4 = lane >> 4, c4 = lane & 15;
    #pragma unroll
    for (int it = 0; it < 4; ++it) {
        int rloc = it * 4 + rr4;
        int r = w16 + rloc;
        int sr = __shfl(s_l, r);
        int dr = __shfl(d_l, r);
        uint2 vs = *(const uint2*)&fb[(size_t)sr * 64 + c4 * 4];
        uint2 vd = *(const uint2*)&fb[(size_t)dr * 64 + c4 * 4];
        *(uint2*)&Xw[rloc*168 + c4*4]      = vs;
        *(uint2*)&Xw[rloc*168 + 64 + c4*4] = vd;
        if (c4 < 8) {
            uint2 vz = make_uint2(0u, 0u);
            if (c4 == 0) {
                float4 iv = *(const float4*)&ivb[r * 8];
                vz = make_uint2(pk2u(iv.x, iv.y), pk2u(iv.z, iv.w));
            }
            *(uint2*)&Xw[rloc*168 + 128 + c4*4] = vz;
        }
    }

    // ================= layer 1: MFMA, K=160 (invariants in-band) ============
    float4v acc[4];
    #pragma unroll
    for (int nt = 0; nt < 4; ++nt) {
        float bv = b1[nt*16 + l16];
        acc[nt] = (float4v){bv, bv, bv, bv};
    }
    #pragma unroll
    for (int kk = 0; kk < 5; ++kk) {
        short8 a = *(const short8*)&Xw[l16*168 + kk*32 + q*8];
        #pragma unroll
        for (int nt = 0; nt < 4; ++nt) {
            short8 bf = *(const short8*)&wbuf[W1S_OFF + (((kk*4 + nt)*64) + lane) * 8];
            acc[nt] = __builtin_amdgcn_mfma_f32_16x16x32_bf16(a, bf, acc[nt], 0, 0, 0);
        }
    }
    #pragma unroll
    for (int nt = 0; nt < 4; ++nt)
        #pragma unroll
        for (int i = 0; i < 4; ++i)
            Hw[(q*4 + i)*72 + nt*16 + l16] = f2b(silu_(acc[nt][i]));

    // ================= layer 2 + gate: shared A-fragments ===================
    float4v mac[4], gac[4];
    #pragma unroll
    for (int nt = 0; nt < 4; ++nt) {
        float bv = b2[nt*16 + l16];
        float gv = gateb[nt*16 + l16];
        mac[nt] = (float4v){bv, bv, bv, bv};
        gac[nt] = (float4v){gv, gv, gv, gv};
    }
    #pragma unroll
    for (int kk = 0; kk < 2; ++kk) {
        short8 a = *(const short8*)&Hw[l16*72 + kk*32 + q*8];
        #pragma unroll
        for (int nt = 0; nt < 4; ++nt) {
            short8 bf = *(const short8*)&wbuf[W2S_OFF + (((kk*4 + nt)*64) + lane) * 8];
            mac[nt] = __builtin_amdgcn_mfma_f32_16x16x32_bf16(a, bf, mac[nt], 0, 0, 0);
        }
        #pragma unroll
        for (int nt = 0; nt < 4; ++nt) {
            short8 bf = *(const short8*)&wbuf[P1S_OFF + (((kk*4 + nt)*64) + lane) * 8];
            gac[nt] = __builtin_amdgcn_mfma_f32_16x16x32_bf16(a, bf, gac[nt], 0, 0, 0);
        }
    }

    // M -> LDS as fp32 (lane-transpose for the segmented column sums)
    #pragma unroll
    for (int nt = 0; nt < 4; ++nt)
        #pragma unroll
        for (int i = 0; i < 4; ++i)
            Mw[(q*4 + i)*68 + nt*16 + l16] = mac[nt][i];

    // ================= gate eval: wt per row ================================
    float p2v[4];
    #pragma unroll
    for (int nt = 0; nt < 4; ++nt) p2v[nt] = P2[nt*16 + l16];
    const float pb2v = pb2[0];

    float wt_i[4];
    #pragma unroll
    for (int i = 0; i < 4; ++i) {
        float p = 0.f;
        #pragma unroll
        for (int nt = 0; nt < 4; ++nt) p += silu_(gac[nt][i]) * p2v[nt];
        p += __shfl_xor(p, 8);
        p += __shfl_xor(p, 4);
        p += __shfl_xor(p, 2);
        p += __shfl_xor(p, 1);
        wt_i[i] = tanh_fast_(p + pb2v);     // valid in all 16 lanes of quad q
    }
    // redistribute: lane l16 gets wt of row l16 (register select + 1 shfl)
    int in_ = l16 & 3, qn = l16 >> 2;
    float wtsel = wt_i[0];
    wtsel = (in_ == 1) ? wt_i[1] : wtsel;
    wtsel = (in_ == 2) ? wt_i[2] : wtsel;
    wtsel = (in_ == 3) ? wt_i[3] : wtsel;
    const float wtl = __shfl(wtsel, (qn << 4) | in_);

    float* aggB = aggf + (size_t)b * C_ * 64;
    float* opB  = out_pos + (size_t)b * C_ * 3;

    // ================= segment boundaries (rows = dst-sorted) ===============
    int dl  = __shfl(d_l, w16 + l16);                  // d of row l16
    int dnx = __shfl(d_l, w16 + ((l16 + 1) & 15));     // d of next row (wrap unused)
    bool isEnd = (l16 == 15) || (dl != dnx);
    unsigned long long bm = __ballot(isEnd);           // 4 identical 16-bit groups
    unsigned grp16 = (unsigned)bm & 0xFFFFu;

    // ---- position update via segmented prefix-scan (component = quad) ------
    float gv = wtl * ((q == 0) ? relx : (q == 1) ? rely : relz);
    float Pf = gv;
    #pragma unroll
    for (int s = 1; s < 16; s <<= 1) {
        float n = __shfl_up(Pf, s);
        Pf += (l16 >= s) ? n : 0.f;
    }
    unsigned below = grp16 & ((1u << l16) - 1u);
    int pe = 31 - __clz(below | 1u);                   // prev segment end row
    float Pp = __shfl(Pf, (lane & 48) + pe);
    float segsum = Pf - ((below != 0u) ? Pp : 0.f);
    if (isEnd && q < 3)
        atomicAdd(&opB[(size_t)dl * 3 + q], segsum);

    // ---- message aggregation: fp32 rows from LDS, uniform flush loop -------
    float mrow[16];
    #pragma unroll
    for (int rr = 0; rr < 16; ++rr) mrow[rr] = Mw[rr*68 + lane];

    int dprev = __shfl(d_l, w16);
    float colacc = 0.f;
    #pragma unroll
    for (int rr = 0; rr < 16; ++rr) {
        int dcur = __shfl(d_l, w16 + rr);          // wave-uniform
        if (dcur != dprev) {                       // uniform branch
            atomicAdd(&aggB[(size_t)dprev * 64 + lane], colacc);
            colacc = 0.f;
            dprev = dcur;
        }
        colacc += mrow[rr];
    }
    atomicAdd(&aggB[(size_t)dprev * 64 + lane], colacc);
}

// ---------------------------------------------------------------------------
// Node update via MFMA, barrier-free wave-private strips.
// ---------------------------------------------------------------------------
__global__ __launch_bounds__(256) void node_kernel(
    const float* __restrict__ feat, const unsigned short* __restrict__ featb,
    const float* __restrict__ aggf, const float* __restrict__ deg,
    const unsigned short* __restrict__ wbuf,
    const float* __restrict__ ub1, const float* __restrict__ ub2,
    float* __restrict__ out_feat)
{
    __shared__ unsigned short lds[4 * 3328];

    const int tid  = threadIdx.x;
    const int w    = tid >> 6;
    const int lane = tid & 63;
    const int q    = lane >> 4;
    const int l16  = lane & 15;
    const int g0   = blockIdx.x * 64;

    unsigned short* Xw = lds + w * 3328;
    unsigned short* Hw = Xw + 2176;

    const int rr4 = lane >> 4, c4 = lane & 15;
    #pragma unroll
    for (int it = 0; it < 4; ++it) {
        int rloc = it * 4 + rr4;
        int g = g0 + w*16 + rloc;
        int gc = (g >= C_) ? g - C_ : g;
        float sc = 1.f / fmaxf(deg[gc], 1.f);
        uint2  vf = *(const uint2*)&featb[(size_t)g * 64 + c4 * 4];
        float4 va = *(const float4*)&aggf[(size_t)g * 64 + c4 * 4];
        *(uint2*)&Xw[rloc*136 + c4*4]      = vf;
        *(uint2*)&Xw[rloc*136 + 64 + c4*4] =
            make_uint2(pk2u(va.x*sc, va.y*sc), pk2u(va.z*sc, va.w*sc));
    }

    float4v acc[4];
    #pragma unroll
    for (int nt = 0; nt < 4; ++nt) {
        float bv = ub1[nt*16 + l16];
        acc[nt] = (float4v){bv, bv, bv, bv};
    }
    #pragma unroll
    for (int kk = 0; kk < 4; ++kk) {
        short8 a = *(const short8*)&Xw[l16*136 + kk*32 + q*8];
        #pragma unroll
        for (int nt = 0; nt < 4; ++nt) {
            short8 bf = *(const short8*)&wbuf[U1S_OFF + (((kk*4 + nt)*64) + lane) * 8];
            acc[nt] = __builtin_amdgcn_mfma_f32_16x16x32_bf16(a, bf, acc[nt], 0, 0, 0);
        }
    }
    #pragma unroll
    for (int nt = 0; nt < 4; ++nt)
        #pragma unroll
        for (int i = 0; i < 4; ++i)
            Hw[(q*4 + i)*72 + nt*16 + l16] = f2b(silu_(acc[nt][i]));

    float4v oac[4];
    #pragma unroll
    for (int nt = 0; nt < 4; ++nt) {
        float bv = ub2[nt*16 + l16];
        oac[nt] = (float4v){bv, bv, bv, bv};
    }
    #pragma unroll
    for (int kk = 0; kk < 2; ++kk) {
        short8 a = *(const short8*)&Hw[l16*72 + kk*32 + q*8];
        #pragma unroll
        for (int nt = 0; nt < 4; ++nt) {
            short8 bf = *(const short8*)&wbuf[U2S_OFF + (((kk*4 + nt)*64) + lane) * 8];
            oac[nt] = __builtin_amdgcn_mfma_f32_16x16x32_bf16(a, bf, oac[nt], 0, 0, 0);
        }
    }
    #pragma unroll
    for (int nt = 0; nt < 4; ++nt)
        #pragma unroll
        for (int i = 0; i < 4; ++i) {
            size_t idx = (size_t)(g0 + w*16 + q*4 + i) * 64 + nt*16 + l16;
            out_feat[idx] = feat[idx] + oac[nt][i];
        }
}

extern "C" void kernel_launch(void* const* d_in, const int* in_sizes, int n_in,
                              void* d_out, int out_size, void* d_ws, size_t ws_size,
                              hipStream_t stream) {
    const float* feat = (const float*)d_in[0];
    const float* pos  = (const float*)d_in[1];
    const int*   ei   = (const int*)d_in[2];
    const float* deg  = (const float*)d_in[3];
    const int*   cni  = (const int*)d_in[4];
    const float* mask = (const float*)d_in[5];
    const float* W1   = (const float*)d_in[6];
    const float* b1   = (const float*)d_in[7];
    const float* W2   = (const float*)d_in[8];
    const float* b2   = (const float*)d_in[9];
    const float* P1   = (const float*)d_in[10];
    const float* pb1  = (const float*)d_in[11];
    const float* P2   = (const float*)d_in[12];
    const float* pb2  = (const float*)d_in[13];
    const float* U1   = (const float*)d_in[14];
    const float* ub1  = (const float*)d_in[15];
    const float* U2   = (const float*)d_in[16];
    const float* ub2  = (const float*)d_in[17];

    float* out_feat = (float*)d_out;                       // B*C*H
    float* out_pos  = out_feat + (size_t)B_ * C_ * H_;     // B*C*P

    // workspace layout (~34 MB)
    float* aggf = (float*)d_ws;                                  // B*C*64 fp32
    unsigned short* featb = (unsigned short*)(aggf + (size_t)B_ * C_ * 64); // B*C*64
    unsigned short* descb = featb + (size_t)B_ * C_ * 64;        // B*C*40 bf16
    unsigned short* wbuf  = descb + (size_t)B_ * C_ * 40;        // 30720
    float* gateb = (float*)(wbuf + WBUF_ELEMS);                  // 64 fp32
    int* cnt    = (int*)(gateb + 64);                            // C
    int* total  = cnt + C_;                                      // 4 (pad)
    int* cursor = total + 4;                                     // C
    int2* sedge = (int2*)(cursor + C_);                          // E int2
    float* inv8 = (float*)(sedge + E_);                          // B*E*8 fp32

    hipMemsetAsync(cnt, 0, (C_ + 4) * sizeof(int), stream);      // cnt + total

    combo_kernel<<<NB_COMBO, 256, 0, stream>>>(
        W1, W2, P1, U1, U2, wbuf, feat, featb, pos, cni, mask, descb, ei, cnt,
        b2, pb1, gateb);

    alloc_kernel<<<(C_ + 255) / 256, 256, 0, stream>>>(cnt, cursor, total);
    scatter_kernel<<<(E_ + 255) / 256, 256, 0, stream>>>(ei, cursor, sedge);

    geom_kernel<<<NB_GEOMK, 256, 0, stream>>>(sedge, descb, inv8, aggf, pos, out_pos);

    edge_kernel<<<B_ * ET_, 256, 0, stream>>>(
        featb, sedge, inv8, wbuf, b1, b2, gateb, P2, pb2, aggf, out_pos);

    node_kernel<<<(B_ * C_) / 64, 256, 0, stream>>>(
        feat, featb, aggf, deg, wbuf, ub1, ub2, out_feat);
}